// Round 10
// baseline (3373.874 us; speedup 1.0000x reference)
//
#include <hip/hip_runtime.h>
#include <hip/hip_bf16.h>

#define H 128
#define NN 50000
#define NE 500000
#define NB 64
#define NSTEPS 3
#define LROW 136  // 128 + 8 pad
#define STRIP ((NN + 255) / 256)

typedef __bf16 bf16x8 __attribute__((ext_vector_type(8)));
typedef __bf16 bf16x2 __attribute__((ext_vector_type(2)));
typedef float f32x4 __attribute__((ext_vector_type(4)));

// frag-layout trait: bf16 staged weights use fragment-major layout; f32 fallback = row-major
template <typename T> struct IsFrag { static constexpr bool v = false; };
template <> struct IsFrag<__bf16> { static constexpr bool v = true; };

__device__ __forceinline__ f32x4 mfma16(bf16x8 a, bf16x8 b, f32x4 c) {
  return __builtin_amdgcn_mfma_f32_16x16x32_bf16(a, b, c, 0, 0, 0);
}
__device__ __forceinline__ float sigm(float x) { return 1.f / (1.f + __expf(-x)); }
__device__ __forceinline__ float tanh_(float x) { return 1.f - 2.f / (1.f + __expf(2.f * x)); }
__device__ __forceinline__ bf16x8 cvt8s(float4 lo, float4 hi, float s) {
  bf16x8 v;
  v[0] = (__bf16)(lo.x * s); v[1] = (__bf16)(lo.y * s);
  v[2] = (__bf16)(lo.z * s); v[3] = (__bf16)(lo.w * s);
  v[4] = (__bf16)(hi.x * s); v[5] = (__bf16)(hi.y * s);
  v[6] = (__bf16)(hi.z * s); v[7] = (__bf16)(hi.w * s);
  return v;
}
__device__ __forceinline__ bf16x8 g8(const __bf16* p) { return *reinterpret_cast<const bf16x8*>(p); }
__device__ __forceinline__ bf16x8 g8(const float* p) {
  float4 lo = *(const float4*)p, hi = *(const float4*)(p + 4);
  return cvt8s(lo, hi, 1.f);
}
__device__ __forceinline__ bf16x8 zero8() {
  bf16x8 v;
#pragma unroll
  for (int i = 0; i < 8; ++i) v[i] = (__bf16)0.f;
  return v;
}
// fragment-major weight load: fragment group fg = rb*(C/32)+cb, lane-contiguous 16B
__device__ __forceinline__ bf16x8 gw(const __bf16* w, int fg, int lane) {
  return *reinterpret_cast<const bf16x8*>(w + ((size_t)fg * 64 + lane) * 8);
}

// ---------------- weight staging: 12 f32 matrices -> bf16 frag-major in ws ----------------
#define OW_EW1 0
#define OW_EW2 65536
#define OW_NW1 81920
#define OW_NW2 131072
#define OW_GW1 147456
#define OW_GW2 180224
#define OW_EWIH 196608
#define OW_EWHH 245760
#define OW_NWIH 294912
#define OW_NWHH 344064
#define OW_GWIH 393216
#define OW_GWHH 442368
#define OW_TOTAL 491520

struct W12 { const float* p[12]; };

// frag-major reorder: dest elem o in matrix s:
//   fg = o/512, lane = (o/8)%64, e = o%8
//   rb = fg/(C/32), cb = fg%(C/32)
//   src (r,c) = (rb*16 + (lane&15), cb*32 + (lane>>4)*8 + e)
__global__ __launch_bounds__(256) void cvt_kernel(W12 w, __bf16* __restrict__ out) {
  const int off[13] = {OW_EW1, OW_EW2, OW_NW1, OW_NW2, OW_GW1, OW_GW2,
                       OW_EWIH, OW_EWHH, OW_NWIH, OW_NWHH, OW_GWIH, OW_GWHH, OW_TOTAL};
  const int Cs[12] = {512, 128, 384, 128, 256, 128, 128, 128, 128, 128, 128, 128};
  int e = (blockIdx.x * 256 + threadIdx.x) * 8;
  if (e >= OW_TOTAL) return;
  int s = 0;
#pragma unroll
  for (int i = 1; i < 12; ++i)
    if (e >= off[i]) s = i;
  const int C = Cs[s];
  const int local = e - off[s];
  const int fg = local >> 9;           // /512
  const int lane = (local >> 3) & 63;  // lane within fragment group
  const int nb = C >> 5;               // C/32
  const int rb = fg / nb, cb = fg - rb * nb;
  const int r = rb * 16 + (lane & 15);
  const int c = cb * 32 + (lane >> 4) * 8;
  const float* src = w.p[s] + (size_t)r * C + c;
  float4 lo = *(const float4*)src, hi = *(const float4*)(src + 4);
  *reinterpret_cast<bf16x8*>(out + e) = cvt8s(lo, hi, 1.f);
}

// generic f32 -> bf16 buffer mirror (counts divisible by 8)
__global__ __launch_bounds__(256) void cvtbuf_kernel(const float* __restrict__ src,
                                                     __bf16* __restrict__ dst, long n) {
  long i = ((long)blockIdx.x * 256 + threadIdx.x) * 8;
  if (i >= n) return;
  float4 lo = *(const float4*)(src + i), hi = *(const float4*)(src + i + 4);
  *reinterpret_cast<bf16x8*>(dst + i) = cvt8s(lo, hi, 1.f);
}

__global__ void count_kernel(const int* __restrict__ dst, const int* __restrict__ batch,
                             int* __restrict__ dcnt, int* __restrict__ ncnt) {
  int i = blockIdx.x * 256 + threadIdx.x;
  if (i < NE) atomicAdd(&dcnt[dst[i]], 1);
  if (i < NN) atomicAdd(&ncnt[batch[i]], 1);
}

// ---------------- CSR build (once; graph static across steps) ----------------
__global__ __launch_bounds__(256) void scan_kernel(const int* __restrict__ dcnt,
                                                   const int* __restrict__ ncnt,
                                                   int* __restrict__ rowptr,   // NN+1
                                                   int* __restrict__ growptr,  // NB+1
                                                   int* __restrict__ fill) {
  __shared__ int ssum[256];
  const int t = threadIdx.x;
  const int b0 = t * STRIP;
  const int b1 = min(b0 + STRIP, NN);
  int s = 0;
  for (int i = b0; i < b1; ++i) s += dcnt[i];
  ssum[t] = s;
  __syncthreads();
  if (t == 0) {
    int run = 0;
    for (int i = 0; i < 256; ++i) { int v = ssum[i]; ssum[i] = run; run += v; }
  }
  __syncthreads();
  int off = ssum[t];
  for (int i = b0; i < b1; ++i) { rowptr[i] = off; off += dcnt[i]; fill[i] = 0; }
  if (b1 == NN) rowptr[NN] = off;
  if (t == 0) {
    int run = 0;
    for (int g = 0; g < NB; ++g) { growptr[g] = run; run += ncnt[g]; }
    growptr[NB] = run;
  }
}

__global__ __launch_bounds__(256) void scatter_kernel(const int* __restrict__ dst,
                                                      const int* __restrict__ rowptr,
                                                      int* __restrict__ fill,
                                                      int* __restrict__ eids) {
  int i = blockIdx.x * 256 + threadIdx.x;
  if (i >= NE) return;
  int d = dst[i];
  int pos = rowptr[d] + atomicAdd(&fill[d], 1);
  eids[pos] = i;
}

// -------- per-step gather aggregation: aggb[v] = bf16(mean(ea[in-edges])) ----
__global__ __launch_bounds__(256) void agg_kernel(const float* __restrict__ ea,
                                                  const int* __restrict__ rowptr,
                                                  const int* __restrict__ eids,
                                                  __bf16* __restrict__ aggb) {
  const int wave = threadIdx.x >> 6, lane = threadIdx.x & 63;
  const int v = blockIdx.x * 4 + wave;
  if (v >= NN) return;
  const int beg = rowptr[v], end = rowptr[v + 1];
  const int deg = end - beg;
  float ax = 0.f, ay = 0.f;
  for (int base = beg; base < end; base += 64) {
    const int nb = min(64, end - base);
    const int le = (base + lane < end) ? eids[base + lane] : 0;
#pragma unroll 4
    for (int e = 0; e < nb; ++e) {
      const int eid = __shfl(le, e, 64);
      const float2 val = *reinterpret_cast<const float2*>(ea + (size_t)eid * H + lane * 2);
      ax += val.x; ay += val.y;
    }
  }
  const float inv = 1.f / (float)max(deg, 1);
  bf16x2 o;
  o[0] = (__bf16)(ax * inv);
  o[1] = (__bf16)(ay * inv);
  *reinterpret_cast<bf16x2*>(aggb + (size_t)v * H + lane * 2) = o;
}

// ---------------- per-step per-graph node sum (batch sorted) -----------------
__global__ __launch_bounds__(256) void xsum_kernel(const float* __restrict__ x,
                                                   const int* __restrict__ growptr,
                                                   float* __restrict__ xsum) {
  __shared__ float part[256];
  const int g = blockIdx.x;
  const int t = threadIdx.x;
  const int col = t & 127, half = t >> 7;
  const int beg = growptr[g], end = growptr[g + 1];
  float s = 0.f;
  for (int r = beg + half; r < end; r += 2) s += x[(size_t)r * H + col];
  part[t] = s;
  __syncthreads();
  if (half == 0) xsum[g * H + col] = part[col] + part[128 + col];
}

// -------- edge model: MLP(4H->H->H) + GRU, per-wave M=64 (4x16-row tiles) ----
template <typename WT>
__global__ __launch_bounds__(256, 2) void edge_kernel(
    const WT* __restrict__ xv, const int* __restrict__ ei,
    float* __restrict__ ea,
    const WT* __restrict__ uv, const int* __restrict__ batch,
    const WT* __restrict__ w1, const float* __restrict__ b1,
    const WT* __restrict__ w2, const float* __restrict__ b2,
    const WT* __restrict__ wih, const WT* __restrict__ whh,
    const float* __restrict__ bih, const float* __restrict__ bhh) {
  __shared__ __bf16 lds[4][64 * LROW];   // 69,632 B/block -> 2 blocks/CU
  const int* src = ei;
  const int* dst = ei + NE;
  const int wave = threadIdx.x >> 6, lane = threadIdx.x & 63;
  const int lm = lane & 15, quad = lane >> 4;
  const long base = ((long)blockIdx.x * 4 + wave) * 64;
  __bf16* myl = lds[wave];

  int eA[4], sA[4], dA[4], gA[4];
#pragma unroll
  for (int j = 0; j < 4; ++j) {
    long t = base + j * 16 + lm;
    eA[j] = (int)(t < NE ? t : NE - 1);
    sA[j] = src[eA[j]];
    dA[j] = dst[eA[j]];
    gA[j] = batch[sA[j]];
  }

  // ---- layer 1: K = 512 over 4 gathered segments ----
  f32x4 acc[8][4] = {};
#pragma unroll
  for (int seg = 0; seg < 4; ++seg) {
#pragma unroll
    for (int ss = 0; ss < 4; ++ss) {
      const int kk = ss * 32 + quad * 8;
      bf16x8 a[4];
#pragma unroll
      for (int j = 0; j < 4; ++j) {
        if (seg == 0)      a[j] = g8(xv + (size_t)sA[j] * H + kk);
        else if (seg == 1) a[j] = g8(xv + (size_t)dA[j] * H + kk);
        else if (seg == 2) a[j] = g8(ea + (size_t)eA[j] * H + kk);
        else               a[j] = g8(uv + (size_t)gA[j] * H + kk);
      }
#pragma unroll
      for (int n = 0; n < 8; ++n) {
        bf16x8 bf;
        if constexpr (IsFrag<WT>::v) bf = gw(w1, n * 16 + seg * 4 + ss, lane);  // C=512: n*(512/32)
        else                         bf = g8(w1 + (n * 16 + lm) * 512 + seg * 128 + kk);
#pragma unroll
        for (int j = 0; j < 4; ++j) acc[n][j] = mfma16(a[j], bf, acc[n][j]);
      }
    }
  }
#pragma unroll
  for (int n = 0; n < 8; ++n) {
    const float bb = b1[n * 16 + lm];
#pragma unroll
    for (int j = 0; j < 4; ++j)
#pragma unroll
      for (int r = 0; r < 4; ++r)
        myl[(j * 16 + quad * 4 + r) * LROW + n * 16 + lm] = (__bf16)fmaxf(acc[n][j][r] + bb, 0.f);
  }
  __syncthreads();
  // ---- layer 2 ----
  f32x4 acc2[8][4] = {};
#pragma unroll
  for (int ss = 0; ss < 4; ++ss) {
    const int kk = ss * 32 + quad * 8;
    bf16x8 a2[4];
#pragma unroll
    for (int j = 0; j < 4; ++j) a2[j] = g8(myl + (j * 16 + lm) * LROW + ss * 32 + quad * 8);
#pragma unroll
    for (int n = 0; n < 8; ++n) {
      bf16x8 bf;
      if constexpr (IsFrag<WT>::v) bf = gw(w2, n * 4 + ss, lane);  // C=128: n*4
      else                         bf = g8(w2 + (n * 16 + lm) * H + kk);
#pragma unroll
      for (int j = 0; j < 4; ++j) acc2[n][j] = mfma16(a2[j], bf, acc2[n][j]);
    }
  }
  __syncthreads();
#pragma unroll
  for (int n = 0; n < 8; ++n) {
    const float bb = b2[n * 16 + lm];
#pragma unroll
    for (int j = 0; j < 4; ++j)
#pragma unroll
      for (int r = 0; r < 4; ++r)
        myl[(j * 16 + quad * 4 + r) * LROW + n * 16 + lm] = (__bf16)(acc2[n][j][r] + bb);
  }
  __syncthreads();
  // ---- GRU (r/z gates: i-path and h-path merged into one accumulator) ----
  bf16x8 ao[4][4], ah[4][4];
#pragma unroll
  for (int j = 0; j < 4; ++j)
#pragma unroll
    for (int ss = 0; ss < 4; ++ss) {
      ao[j][ss] = g8(myl + (j * 16 + lm) * LROW + ss * 32 + quad * 8);
      ah[j][ss] = g8(ea + (size_t)eA[j] * H + ss * 32 + quad * 8);  // L2-warm (seg2 lines)
    }
#pragma unroll 1
  for (int n = 0; n < 8; ++n) {
    f32x4 ar[4] = {}, az[4] = {}, aig[4] = {}, ahg[4] = {};
#pragma unroll
    for (int ss = 0; ss < 4; ++ss) {
      bf16x8 wr, wz, wg, vr, vz, vg;
      if constexpr (IsFrag<WT>::v) {
        wr = gw(wih, n * 4 + ss, lane);          // gate r: rb=n
        wz = gw(wih, (8 + n) * 4 + ss, lane);    // gate z: rb=8+n
        wg = gw(wih, (16 + n) * 4 + ss, lane);   // gate g: rb=16+n
        vr = gw(whh, n * 4 + ss, lane);
        vz = gw(whh, (8 + n) * 4 + ss, lane);
        vg = gw(whh, (16 + n) * 4 + ss, lane);
      } else {
        const int wr0 = (n * 16 + lm) * H;
        const int kk = ss * 32 + quad * 8;
        wr = g8(wih + wr0 + kk);
        wz = g8(wih + wr0 + 128 * H + kk);
        wg = g8(wih + wr0 + 256 * H + kk);
        vr = g8(whh + wr0 + kk);
        vz = g8(whh + wr0 + 128 * H + kk);
        vg = g8(whh + wr0 + 256 * H + kk);
      }
#pragma unroll
      for (int j = 0; j < 4; ++j) {
        ar[j] = mfma16(ao[j][ss], wr, ar[j]);
        ar[j] = mfma16(ah[j][ss], vr, ar[j]);
        az[j] = mfma16(ao[j][ss], wz, az[j]);
        az[j] = mfma16(ah[j][ss], vz, az[j]);
        aig[j] = mfma16(ao[j][ss], wg, aig[j]);
        ahg[j] = mfma16(ah[j][ss], vg, ahg[j]);
      }
    }
    const int c = n * 16 + lm;
    const float brm = bih[c] + bhh[c];               // merged r bias
    const float bzm = bih[c + 128] + bhh[c + 128];   // merged z bias
    const float big = bih[c + 256], bhg = bhh[c + 256];
#pragma unroll
    for (int j = 0; j < 4; ++j)
#pragma unroll
      for (int r = 0; r < 4; ++r) {
        long epos = base + j * 16 + quad * 4 + r;
        if (epos < NE) {
          float rg = sigm(ar[j][r] + brm);
          float zg = sigm(az[j][r] + bzm);
          float ng = tanh_(aig[j][r] + big + rg * (ahg[j][r] + bhg));
          size_t off = (size_t)epos * H + c;
          float hold = ea[off];
          float hnew = (1.f - zg) * ng + zg * hold;
          ea[off] = hnew;
        }
      }
  }
}

// ---------------- node model: MLP(3H->H->H) + GRU ----------------
template <typename WT>
__global__ __launch_bounds__(256, 3) void node_kernel(
    float* __restrict__ x, const WT* __restrict__ xv, __bf16* __restrict__ xbm,
    const WT* __restrict__ uv, const int* __restrict__ batch,
    const WT* __restrict__ aggv, int agg_ok,
    const WT* __restrict__ w1, const float* __restrict__ b1,
    const WT* __restrict__ w2, const float* __restrict__ b2,
    const WT* __restrict__ wih, const WT* __restrict__ whh,
    const float* __restrict__ bih, const float* __restrict__ bhh) {
  __shared__ __bf16 lds[4][32 * LROW];
  const int wave = threadIdx.x >> 6, lane = threadIdx.x & 63;
  const int lm = lane & 15, quad = lane >> 4;
  const long base = ((long)blockIdx.x * 4 + wave) * 32;
  __bf16* myl = lds[wave];

  long tA0 = base + lm;      const int iA0 = (int)(tA0 < NN ? tA0 : NN - 1);
  long tA1 = base + 16 + lm; const int iA1 = (int)(tA1 < NN ? tA1 : NN - 1);
  const int g0 = batch[iA0], g1 = batch[iA1];

  f32x4 acc[8][2] = {};
#pragma unroll
  for (int seg = 0; seg < 3; ++seg) {
#pragma unroll
    for (int ss = 0; ss < 4; ++ss) {
      const int kk = ss * 32 + quad * 8;
      bf16x8 a0, a1;
      if (seg == 0) {
        a0 = g8(xv + (size_t)iA0 * H + kk); a1 = g8(xv + (size_t)iA1 * H + kk);
      } else if (seg == 1) {
        if (agg_ok) { a0 = g8(aggv + (size_t)iA0 * H + kk); a1 = g8(aggv + (size_t)iA1 * H + kk); }
        else        { a0 = zero8(); a1 = zero8(); }
      } else {
        a0 = g8(uv + (size_t)g0 * H + kk); a1 = g8(uv + (size_t)g1 * H + kk);
      }
#pragma unroll
      for (int n = 0; n < 8; ++n) {
        bf16x8 bf;
        if constexpr (IsFrag<WT>::v) bf = gw(w1, n * 12 + seg * 4 + ss, lane);  // C=384: n*12
        else                         bf = g8(w1 + (n * 16 + lm) * 384 + seg * 128 + kk);
        acc[n][0] = mfma16(a0, bf, acc[n][0]);
        acc[n][1] = mfma16(a1, bf, acc[n][1]);
      }
    }
  }
#pragma unroll
  for (int n = 0; n < 8; ++n) {
    const float bb = b1[n * 16 + lm];
#pragma unroll
    for (int sub = 0; sub < 2; ++sub)
#pragma unroll
      for (int r = 0; r < 4; ++r) {
        float v = fmaxf(acc[n][sub][r] + bb, 0.f);
        myl[(sub * 16 + quad * 4 + r) * LROW + n * 16 + lm] = (__bf16)v;
      }
  }
  __syncthreads();
  bf16x8 a20[4], a21[4];
#pragma unroll
  for (int ss = 0; ss < 4; ++ss) {
    a20[ss] = g8(myl + lm * LROW + ss * 32 + quad * 8);
    a21[ss] = g8(myl + (16 + lm) * LROW + ss * 32 + quad * 8);
  }
  f32x4 acc2[8][2] = {};
#pragma unroll
  for (int ss = 0; ss < 4; ++ss) {
    const int kk = ss * 32 + quad * 8;
#pragma unroll
    for (int n = 0; n < 8; ++n) {
      bf16x8 bf;
      if constexpr (IsFrag<WT>::v) bf = gw(w2, n * 4 + ss, lane);
      else                         bf = g8(w2 + (n * 16 + lm) * H + kk);
      acc2[n][0] = mfma16(a20[ss], bf, acc2[n][0]);
      acc2[n][1] = mfma16(a21[ss], bf, acc2[n][1]);
    }
  }
  __syncthreads();
#pragma unroll
  for (int n = 0; n < 8; ++n) {
    const float bb = b2[n * 16 + lm];
#pragma unroll
    for (int sub = 0; sub < 2; ++sub)
#pragma unroll
      for (int r = 0; r < 4; ++r)
        myl[(sub * 16 + quad * 4 + r) * LROW + n * 16 + lm] = (__bf16)(acc2[n][sub][r] + bb);
  }
  __syncthreads();
  bf16x8 ao0[4], ao1[4], ah0[4], ah1[4];
#pragma unroll
  for (int ss = 0; ss < 4; ++ss) {
    const int kk = ss * 32 + quad * 8;
    ao0[ss] = g8(myl + lm * LROW + ss * 32 + quad * 8);
    ao1[ss] = g8(myl + (16 + lm) * LROW + ss * 32 + quad * 8);
    ah0[ss] = g8(xv + (size_t)iA0 * H + kk);
    ah1[ss] = g8(xv + (size_t)iA1 * H + kk);
  }
#pragma unroll 2
  for (int n = 0; n < 8; ++n) {
    f32x4 air[2] = {}, aiz[2] = {}, aig[2] = {};
    f32x4 ahr[2] = {}, ahz[2] = {}, ahg[2] = {};
    const int wr0 = (n * 16 + lm) * H;
#pragma unroll
    for (int ss = 0; ss < 4; ++ss) {
      const int kk = ss * 32 + quad * 8;
      bf16x8 wr, wz, wg, vr, vz, vg;
      if constexpr (IsFrag<WT>::v) {
        wr = gw(wih, n * 4 + ss, lane);
        wz = gw(wih, (8 + n) * 4 + ss, lane);
        wg = gw(wih, (16 + n) * 4 + ss, lane);
        vr = gw(whh, n * 4 + ss, lane);
        vz = gw(whh, (8 + n) * 4 + ss, lane);
        vg = gw(whh, (16 + n) * 4 + ss, lane);
      } else {
        wr = g8(wih + wr0 + kk);
        wz = g8(wih + wr0 + 128 * H + kk);
        wg = g8(wih + wr0 + 256 * H + kk);
        vr = g8(whh + wr0 + kk);
        vz = g8(whh + wr0 + 128 * H + kk);
        vg = g8(whh + wr0 + 256 * H + kk);
      }
      air[0] = mfma16(ao0[ss], wr, air[0]); air[1] = mfma16(ao1[ss], wr, air[1]);
      aiz[0] = mfma16(ao0[ss], wz, aiz[0]); aiz[1] = mfma16(ao1[ss], wz, aiz[1]);
      aig[0] = mfma16(ao0[ss], wg, aig[0]); aig[1] = mfma16(ao1[ss], wg, aig[1]);
      ahr[0] = mfma16(ah0[ss], vr, ahr[0]); ahr[1] = mfma16(ah1[ss], vr, ahr[1]);
      ahz[0] = mfma16(ah0[ss], vz, ahz[0]); ahz[1] = mfma16(ah1[ss], vz, ahz[1]);
      ahg[0] = mfma16(ah0[ss], vg, ahg[0]); ahg[1] = mfma16(ah1[ss], vg, ahg[1]);
    }
    const int c = n * 16 + lm;
    const float bir = bih[c], biz = bih[c + 128], big = bih[c + 256];
    const float bhr = bhh[c], bhz = bhh[c + 128], bhg = bhh[c + 256];
#pragma unroll
    for (int sub = 0; sub < 2; ++sub)
#pragma unroll
      for (int r = 0; r < 4; ++r) {
        long ipos = base + sub * 16 + quad * 4 + r;
        if (ipos < NN) {
          float rg = sigm(air[sub][r] + bir + ahr[sub][r] + bhr);
          float zg = sigm(aiz[sub][r] + biz + ahz[sub][r] + bhz);
          float ng = tanh_(aig[sub][r] + big + rg * (ahg[sub][r] + bhg));
          size_t off = (size_t)ipos * H + c;
          float hold = x[off];
          float hnew = (1.f - zg) * ng + zg * hold;
          x[off] = hnew;
          if (xbm) xbm[off] = (__bf16)hnew;
        }
      }
  }
}

// ---------------- global model: MLP(2H->H->H) + GRU, 1 block ----------------
template <typename WT>
__global__ __launch_bounds__(256) void glob_kernel(
    float* __restrict__ u, const WT* __restrict__ uv, __bf16* __restrict__ ubm,
    const float* __restrict__ xsum, const int* __restrict__ ncnt,
    const WT* __restrict__ w1, const float* __restrict__ b1,
    const WT* __restrict__ w2, const float* __restrict__ b2,
    const WT* __restrict__ wih, const WT* __restrict__ whh,
    const float* __restrict__ bih, const float* __restrict__ bhh,
    float* __restrict__ out, int t, int ws_ok) {
  __shared__ __bf16 lds[4][16 * LROW];
  const int wave = threadIdx.x >> 6, lane = threadIdx.x & 63;
  const int lm = lane & 15, quad = lane >> 4;
  __bf16* myl = lds[wave];
  const int row = wave * 16 + lm;
  const float inv = ws_ok ? 1.f / fmaxf((float)ncnt[row], 1.f) : 1.f;

  f32x4 acc[8] = {};
  bf16x8 ah[4];
#pragma unroll
  for (int seg = 0; seg < 2; ++seg) {
#pragma unroll
    for (int ss = 0; ss < 4; ++ss) {
      const int kk = ss * 32 + quad * 8;
      bf16x8 a;
      if (seg == 0) {
        a = g8(uv + row * H + kk);
        ah[ss] = a;
      } else if (ws_ok) {
        float4 lo = *(const float4*)(xsum + row * H + kk);
        float4 hi = *(const float4*)(xsum + row * H + kk + 4);
        a = cvt8s(lo, hi, inv);
      } else {
        a = zero8();
      }
#pragma unroll
      for (int n = 0; n < 8; ++n) {
        bf16x8 bf;
        if constexpr (IsFrag<WT>::v) bf = gw(w1, n * 8 + seg * 4 + ss, lane);  // C=256: n*8
        else                         bf = g8(w1 + (n * 16 + lm) * 256 + seg * 128 + kk);
        acc[n] = mfma16(a, bf, acc[n]);
      }
    }
  }
#pragma unroll
  for (int n = 0; n < 8; ++n) {
    const float bb = b1[n * 16 + lm];
#pragma unroll
    for (int r = 0; r < 4; ++r)
      myl[(quad * 4 + r) * LROW + n * 16 + lm] = (__bf16)fmaxf(acc[n][r] + bb, 0.f);
  }
  __syncthreads();
  bf16x8 a2[4];
#pragma unroll
  for (int ss = 0; ss < 4; ++ss) a2[ss] = g8(myl + lm * LROW + ss * 32 + quad * 8);
  f32x4 acc2[8] = {};
#pragma unroll
  for (int ss = 0; ss < 4; ++ss) {
    const int kk = ss * 32 + quad * 8;
#pragma unroll
    for (int n = 0; n < 8; ++n) {
      bf16x8 bf;
      if constexpr (IsFrag<WT>::v) bf = gw(w2, n * 4 + ss, lane);
      else                         bf = g8(w2 + (n * 16 + lm) * H + kk);
      acc2[n] = mfma16(a2[ss], bf, acc2[n]);
    }
  }
  __syncthreads();
#pragma unroll
  for (int n = 0; n < 8; ++n) {
    const float bb = b2[n * 16 + lm];
#pragma unroll
    for (int r = 0; r < 4; ++r)
      myl[(quad * 4 + r) * LROW + n * 16 + lm] = (__bf16)(acc2[n][r] + bb);
  }
  __syncthreads();
  bf16x8 ao[4];
#pragma unroll
  for (int ss = 0; ss < 4; ++ss) ao[ss] = g8(myl + lm * LROW + ss * 32 + quad * 8);
  for (int n = 0; n < 8; ++n) {
    f32x4 air = {}, aiz = {}, aig = {}, ahr = {}, ahz = {}, ahg = {};
    const int wr0 = (n * 16 + lm) * H;
#pragma unroll
    for (int ss = 0; ss < 4; ++ss) {
      const int kk = ss * 32 + quad * 8;
      bf16x8 wr, wz, wg, vr, vz, vg;
      if constexpr (IsFrag<WT>::v) {
        wr = gw(wih, n * 4 + ss, lane);
        wz = gw(wih, (8 + n) * 4 + ss, lane);
        wg = gw(wih, (16 + n) * 4 + ss, lane);
        vr = gw(whh, n * 4 + ss, lane);
        vz = gw(whh, (8 + n) * 4 + ss, lane);
        vg = gw(whh, (16 + n) * 4 + ss, lane);
      } else {
        wr = g8(wih + wr0 + kk);
        wz = g8(wih + wr0 + 128 * H + kk);
        wg = g8(wih + wr0 + 256 * H + kk);
        vr = g8(whh + wr0 + kk);
        vz = g8(whh + wr0 + 128 * H + kk);
        vg = g8(whh + wr0 + 256 * H + kk);
      }
      air = mfma16(ao[ss], wr, air);
      aiz = mfma16(ao[ss], wz, aiz);
      aig = mfma16(ao[ss], wg, aig);
      ahr = mfma16(ah[ss], vr, ahr);
      ahz = mfma16(ah[ss], vz, ahz);
      ahg = mfma16(ah[ss], vg, ahg);
    }
    const int c = n * 16 + lm;
    const float bir = bih[c], biz = bih[c + 128], big = bih[c + 256];
    const float bhr = bhh[c], bhz = bhh[c + 128], bhg = bhh[c + 256];
#pragma unroll
    for (int r = 0; r < 4; ++r) {
      const int rowC = wave * 16 + quad * 4 + r;
      float rg = sigm(air[r] + bir + ahr[r] + bhr);
      float zg = sigm(aiz[r] + biz + ahz[r] + bhz);
      float ng = tanh_(aig[r] + big + rg * (ahg[r] + bhg));
      float hold = u[rowC * H + c];
      float hnew = (1.f - zg) * ng + zg * hold;
      u[rowC * H + c] = hnew;
      if (ubm) ubm[rowC * H + c] = (__bf16)hnew;
      out[(rowC * NSTEPS + t) * H + c] = hnew;
    }
  }
}

extern "C" void kernel_launch(void* const* d_in, const int* in_sizes, int n_in,
                              void* d_out, int out_size, void* d_ws, size_t ws_size,
                              hipStream_t stream) {
  float* x = (float*)d_in[0];
  const int* ei = (const int*)d_in[1];
  float* ea = (float*)d_in[2];
  float* u = (float*)d_in[3];
  const int* batch = (const int*)d_in[4];
  float* out = (float*)d_out;

  // ---- workspace layout ----
  char* ws = (char*)d_ws;
  size_t off = 0;
  auto alloc = [&](size_t bytes, size_t align) {
    off = (off + align - 1) & ~(align - 1);
    size_t r = off; off += bytes; return r;
  };
  __bf16* aggb   = (__bf16*)(ws + alloc((size_t)NN * H * 2, 16));
  float*  xsum   = (float*) (ws + alloc((size_t)NB * H * 4, 16));
  int*    dcnt   = (int*)   (ws + alloc((size_t)NN * 4, 4));
  int*    ncnt   = (int*)   (ws + alloc((size_t)NB * 4, 4));   // contiguous w/ dcnt
  int*    rowptr = (int*)   (ws + alloc((size_t)(NN + 1) * 4, 4));
  int*    growptr= (int*)   (ws + alloc((size_t)(NB + 1) * 4, 4));
  int*    fill   = (int*)   (ws + alloc((size_t)NN * 4, 4));
  int*    eids   = (int*)   (ws + alloc((size_t)NE * 4, 4));
  __bf16* wbuf   = (__bf16*)(ws + alloc((size_t)OW_TOTAL * 2, 16));
  __bf16* xb     = (__bf16*)(ws + alloc((size_t)NN * H * 2, 16));
  __bf16* ub     = (__bf16*)(ws + alloc((size_t)NB * H * 2, 16));
  const size_t need_base = off;
  const int ws_ok = (ws_size >= need_base) ? 1 : 0;

  if (ws_ok) {
    W12 w;
    w.p[0] = (const float*)d_in[5];   // ew1
    w.p[1] = (const float*)d_in[7];   // ew2
    w.p[2] = (const float*)d_in[9];   // nw1
    w.p[3] = (const float*)d_in[11];  // nw2
    w.p[4] = (const float*)d_in[13];  // gw1
    w.p[5] = (const float*)d_in[15];  // gw2
    w.p[6] = (const float*)d_in[17];  // ewih
    w.p[7] = (const float*)d_in[18];  // ewhh
    w.p[8] = (const float*)d_in[21];  // nwih
    w.p[9] = (const float*)d_in[22];  // nwhh
    w.p[10] = (const float*)d_in[25]; // gwih
    w.p[11] = (const float*)d_in[26]; // gwhh
    cvt_kernel<<<(OW_TOTAL / 8 + 255) / 256, 256, 0, stream>>>(w, wbuf);
    hipMemsetAsync(dcnt, 0, (NN + NB) * sizeof(int), stream);
    count_kernel<<<(NE + 255) / 256, 256, 0, stream>>>(ei + NE, batch, dcnt, ncnt);
    scan_kernel<<<1, 256, 0, stream>>>(dcnt, ncnt, rowptr, growptr, fill);
    scatter_kernel<<<(NE + 255) / 256, 256, 0, stream>>>(ei + NE, rowptr, fill, eids);
    // activation bf16 mirrors (x, u only — ea stays f32, see R4 post-mortem)
    cvtbuf_kernel<<<((long)NN * H / 8 + 255) / 256, 256, 0, stream>>>(x, xb, (long)NN * H);
    cvtbuf_kernel<<<((long)NB * H / 8 + 255) / 256, 256, 0, stream>>>(u, ub, (long)NB * H);
  }

  for (int t = 0; t < NSTEPS; ++t) {
    if (ws_ok) {
      edge_kernel<__bf16><<<(NE + 255) / 256, 256, 0, stream>>>(
          xb, ei, ea, ub, batch,
          wbuf + OW_EW1, (const float*)d_in[6], wbuf + OW_EW2, (const float*)d_in[8],
          wbuf + OW_EWIH, wbuf + OW_EWHH, (const float*)d_in[19], (const float*)d_in[20]);
      agg_kernel<<<(NN + 3) / 4, 256, 0, stream>>>(ea, rowptr, eids, aggb);
      node_kernel<__bf16><<<(NN + 127) / 128, 256, 0, stream>>>(
          x, xb, xb, ub, batch, aggb, 1,
          wbuf + OW_NW1, (const float*)d_in[10], wbuf + OW_NW2, (const float*)d_in[12],
          wbuf + OW_NWIH, wbuf + OW_NWHH, (const float*)d_in[23], (const float*)d_in[24]);
      xsum_kernel<<<NB, 256, 0, stream>>>(x, growptr, xsum);
      glob_kernel<__bf16><<<1, 256, 0, stream>>>(
          u, ub, ub, xsum, ncnt,
          wbuf + OW_GW1, (const float*)d_in[14], wbuf + OW_GW2, (const float*)d_in[16],
          wbuf + OW_GWIH, wbuf + OW_GWHH, (const float*)d_in[27], (const float*)d_in[28],
          out, t, 1);
    } else {
      // never-taken safety path: raw f32 weights/activations (row-major), no workspace
      edge_kernel<float><<<(NE + 255) / 256, 256, 0, stream>>>(
          x, ei, ea, u, batch,
          (const float*)d_in[5], (const float*)d_in[6], (const float*)d_in[7], (const float*)d_in[8],
          (const float*)d_in[17], (const float*)d_in[18], (const float*)d_in[19], (const float*)d_in[20]);
      node_kernel<float><<<(NN + 127) / 128, 256, 0, stream>>>(
          x, x, nullptr, u, batch, nullptr, 0,
          (const float*)d_in[9], (const float*)d_in[10], (const float*)d_in[11], (const float*)d_in[12],
          (const float*)d_in[21], (const float*)d_in[22], (const float*)d_in[23], (const float*)d_in[24]);
      glob_kernel<float><<<1, 256, 0, stream>>>(
          u, u, nullptr, xsum, ncnt,
          (const float*)d_in[13], (const float*)d_in[14], (const float*)d_in[15], (const float*)d_in[16],
          (const float*)d_in[25], (const float*)d_in[26], (const float*)d_in[27], (const float*)d_in[28],
          out, t, 0);
    }
  }
}

// Round 14
// 3202.236 us; speedup vs baseline: 1.0536x; 1.0536x over previous
//
#include <hip/hip_runtime.h>
#include <hip/hip_bf16.h>

#define H 128
#define NN 50000
#define NE 500000
#define NB 64
#define NSTEPS 3
#define LROW 136  // 128 + 8 pad
#define STRIP ((NN + 255) / 256)

typedef __bf16 bf16x8 __attribute__((ext_vector_type(8)));
typedef __bf16 bf16x2 __attribute__((ext_vector_type(2)));
typedef float f32x4 __attribute__((ext_vector_type(4)));

// frag-layout trait: bf16 staged weights use fragment-major layout; f32 fallback = row-major
template <typename T> struct IsFrag { static constexpr bool v = false; };
template <> struct IsFrag<__bf16> { static constexpr bool v = true; };

__device__ __forceinline__ f32x4 mfma16(bf16x8 a, bf16x8 b, f32x4 c) {
  return __builtin_amdgcn_mfma_f32_16x16x32_bf16(a, b, c, 0, 0, 0);
}
__device__ __forceinline__ float sigm(float x) { return 1.f / (1.f + __expf(-x)); }
__device__ __forceinline__ float tanh_(float x) { return 1.f - 2.f / (1.f + __expf(2.f * x)); }
__device__ __forceinline__ bf16x8 cvt8s(float4 lo, float4 hi, float s) {
  bf16x8 v;
  v[0] = (__bf16)(lo.x * s); v[1] = (__bf16)(lo.y * s);
  v[2] = (__bf16)(lo.z * s); v[3] = (__bf16)(lo.w * s);
  v[4] = (__bf16)(hi.x * s); v[5] = (__bf16)(hi.y * s);
  v[6] = (__bf16)(hi.z * s); v[7] = (__bf16)(hi.w * s);
  return v;
}
__device__ __forceinline__ bf16x8 g8(const __bf16* p) { return *reinterpret_cast<const bf16x8*>(p); }
__device__ __forceinline__ bf16x8 g8(const float* p) {
  float4 lo = *(const float4*)p, hi = *(const float4*)(p + 4);
  return cvt8s(lo, hi, 1.f);
}
__device__ __forceinline__ bf16x8 zero8() {
  bf16x8 v;
#pragma unroll
  for (int i = 0; i < 8; ++i) v[i] = (__bf16)0.f;
  return v;
}
// fragment-major weight load: fragment group fg = rb*(C/32)+cb, lane-contiguous 16B
__device__ __forceinline__ bf16x8 gw(const __bf16* w, int fg, int lane) {
  return *reinterpret_cast<const bf16x8*>(w + ((size_t)fg * 64 + lane) * 8);
}

// ---------------- weight staging: 12 f32 matrices -> bf16 frag-major in ws ----------------
#define OW_EW1 0
#define OW_EW2 65536
#define OW_NW1 81920
#define OW_NW2 131072
#define OW_GW1 147456
#define OW_GW2 180224
#define OW_EWIH 196608
#define OW_EWHH 245760
#define OW_NWIH 294912
#define OW_NWHH 344064
#define OW_GWIH 393216
#define OW_GWHH 442368
#define OW_TOTAL 491520

struct W12 { const float* p[12]; };

// frag-major reorder: dest elem o in matrix s:
//   fg = o/512, lane = (o/8)%64, e = o%8
//   rb = fg/(C/32), cb = fg%(C/32)
//   src (r,c) = (rb*16 + (lane&15), cb*32 + (lane>>4)*8 + e)
__global__ __launch_bounds__(256) void cvt_kernel(W12 w, __bf16* __restrict__ out) {
  const int off[13] = {OW_EW1, OW_EW2, OW_NW1, OW_NW2, OW_GW1, OW_GW2,
                       OW_EWIH, OW_EWHH, OW_NWIH, OW_NWHH, OW_GWIH, OW_GWHH, OW_TOTAL};
  const int Cs[12] = {512, 128, 384, 128, 256, 128, 128, 128, 128, 128, 128, 128};
  int e = (blockIdx.x * 256 + threadIdx.x) * 8;
  if (e >= OW_TOTAL) return;
  int s = 0;
#pragma unroll
  for (int i = 1; i < 12; ++i)
    if (e >= off[i]) s = i;
  const int C = Cs[s];
  const int local = e - off[s];
  const int fg = local >> 9;           // /512
  const int lane = (local >> 3) & 63;  // lane within fragment group
  const int nb = C >> 5;               // C/32
  const int rb = fg / nb, cb = fg - rb * nb;
  const int r = rb * 16 + (lane & 15);
  const int c = cb * 32 + (lane >> 4) * 8;
  const float* src = w.p[s] + (size_t)r * C + c;
  float4 lo = *(const float4*)src, hi = *(const float4*)(src + 4);
  *reinterpret_cast<bf16x8*>(out + e) = cvt8s(lo, hi, 1.f);
}

// generic f32 -> bf16 buffer mirror (counts divisible by 8)
__global__ __launch_bounds__(256) void cvtbuf_kernel(const float* __restrict__ src,
                                                     __bf16* __restrict__ dst, long n) {
  long i = ((long)blockIdx.x * 256 + threadIdx.x) * 8;
  if (i >= n) return;
  float4 lo = *(const float4*)(src + i), hi = *(const float4*)(src + i + 4);
  *reinterpret_cast<bf16x8*>(dst + i) = cvt8s(lo, hi, 1.f);
}

__global__ void count_kernel(const int* __restrict__ dst, const int* __restrict__ batch,
                             int* __restrict__ dcnt, int* __restrict__ ncnt) {
  int i = blockIdx.x * 256 + threadIdx.x;
  if (i < NE) atomicAdd(&dcnt[dst[i]], 1);
  if (i < NN) atomicAdd(&ncnt[batch[i]], 1);
}

// ---------------- CSR build (once; graph static across steps) ----------------
__global__ __launch_bounds__(256) void scan_kernel(const int* __restrict__ dcnt,
                                                   const int* __restrict__ ncnt,
                                                   int* __restrict__ rowptr,   // NN+1
                                                   int* __restrict__ growptr,  // NB+1
                                                   int* __restrict__ fill) {
  __shared__ int ssum[256];
  const int t = threadIdx.x;
  const int b0 = t * STRIP;
  const int b1 = min(b0 + STRIP, NN);
  int s = 0;
  for (int i = b0; i < b1; ++i) s += dcnt[i];
  ssum[t] = s;
  __syncthreads();
  if (t == 0) {
    int run = 0;
    for (int i = 0; i < 256; ++i) { int v = ssum[i]; ssum[i] = run; run += v; }
  }
  __syncthreads();
  int off = ssum[t];
  for (int i = b0; i < b1; ++i) { rowptr[i] = off; off += dcnt[i]; fill[i] = 0; }
  if (b1 == NN) rowptr[NN] = off;
  if (t == 0) {
    int run = 0;
    for (int g = 0; g < NB; ++g) { growptr[g] = run; run += ncnt[g]; }
    growptr[NB] = run;
  }
}

__global__ __launch_bounds__(256) void scatter_kernel(const int* __restrict__ dst,
                                                      const int* __restrict__ rowptr,
                                                      int* __restrict__ fill,
                                                      int* __restrict__ eids) {
  int i = blockIdx.x * 256 + threadIdx.x;
  if (i >= NE) return;
  int d = dst[i];
  int pos = rowptr[d] + atomicAdd(&fill[d], 1);
  eids[pos] = i;
}

// -------- per-step gather aggregation: aggb[v] = bf16(mean(ea[in-edges])) ----
__global__ __launch_bounds__(256) void agg_kernel(const float* __restrict__ ea,
                                                  const int* __restrict__ rowptr,
                                                  const int* __restrict__ eids,
                                                  __bf16* __restrict__ aggb) {
  const int wave = threadIdx.x >> 6, lane = threadIdx.x & 63;
  const int v = blockIdx.x * 4 + wave;
  if (v >= NN) return;
  const int beg = rowptr[v], end = rowptr[v + 1];
  const int deg = end - beg;
  float ax = 0.f, ay = 0.f;
  for (int base = beg; base < end; base += 64) {
    const int nb = min(64, end - base);
    const int le = (base + lane < end) ? eids[base + lane] : 0;
#pragma unroll 4
    for (int e = 0; e < nb; ++e) {
      const int eid = __shfl(le, e, 64);
      const float2 val = *reinterpret_cast<const float2*>(ea + (size_t)eid * H + lane * 2);
      ax += val.x; ay += val.y;
    }
  }
  const float inv = 1.f / (float)max(deg, 1);
  bf16x2 o;
  o[0] = (__bf16)(ax * inv);
  o[1] = (__bf16)(ay * inv);
  *reinterpret_cast<bf16x2*>(aggb + (size_t)v * H + lane * 2) = o;
}

// ---------------- per-step per-graph node sum (batch sorted) -----------------
__global__ __launch_bounds__(256) void xsum_kernel(const float* __restrict__ x,
                                                   const int* __restrict__ growptr,
                                                   float* __restrict__ xsum) {
  __shared__ float part[256];
  const int g = blockIdx.x;
  const int t = threadIdx.x;
  const int col = t & 127, half = t >> 7;
  const int beg = growptr[g], end = growptr[g + 1];
  float s = 0.f;
  for (int r = beg + half; r < end; r += 2) s += x[(size_t)r * H + col];
  part[t] = s;
  __syncthreads();
  if (half == 0) xsum[g * H + col] = part[col] + part[128 + col];
}

// -------- edge model: MLP(4H->H->H) + GRU, per-wave M=32, ea-frag carry ------
template <typename WT>
__global__ __launch_bounds__(256, 3) void edge_kernel(
    const WT* __restrict__ xv, const int* __restrict__ ei,
    float* __restrict__ ea,
    const WT* __restrict__ uv, const int* __restrict__ batch,
    const WT* __restrict__ w1, const float* __restrict__ b1,
    const WT* __restrict__ w2, const float* __restrict__ b2,
    const WT* __restrict__ wih, const WT* __restrict__ whh,
    const float* __restrict__ bih, const float* __restrict__ bhh) {
  __shared__ __bf16 lds[4][32 * LROW];
  const int* src = ei;
  const int* dst = ei + NE;
  const int wave = threadIdx.x >> 6, lane = threadIdx.x & 63;
  const int lm = lane & 15, quad = lane >> 4;
  const long base = ((long)blockIdx.x * 4 + wave) * 32;
  __bf16* myl = lds[wave];

  long tA0 = base + lm;      const int eA0 = (int)(tA0 < NE ? tA0 : NE - 1);
  long tA1 = base + 16 + lm; const int eA1 = (int)(tA1 < NE ? tA1 : NE - 1);
  const int s0 = src[eA0], s1 = src[eA1];
  const int d0 = dst[eA0], d1 = dst[eA1];
  const int g0 = batch[s0], g1 = batch[s1];

  // ---- layer 1: K = 512 over 4 gathered segments; carry ea frags to GRU ----
  f32x4 acc[8][2] = {};
  bf16x8 ah0[4], ah1[4];   // seg2 ea fragments, reused by GRU h-path (no reload)
#pragma unroll
  for (int seg = 0; seg < 4; ++seg) {
#pragma unroll
    for (int ss = 0; ss < 4; ++ss) {
      const int kk = ss * 32 + quad * 8;
      bf16x8 a0, a1;
      if (seg == 0) {
        a0 = g8(xv + (size_t)s0 * H + kk); a1 = g8(xv + (size_t)s1 * H + kk);
      } else if (seg == 1) {
        a0 = g8(xv + (size_t)d0 * H + kk); a1 = g8(xv + (size_t)d1 * H + kk);
      } else if (seg == 2) {
        a0 = g8(ea + (size_t)eA0 * H + kk); a1 = g8(ea + (size_t)eA1 * H + kk);
        ah0[ss] = a0; ah1[ss] = a1;
      } else {
        a0 = g8(uv + (size_t)g0 * H + kk); a1 = g8(uv + (size_t)g1 * H + kk);
      }
#pragma unroll
      for (int n = 0; n < 8; ++n) {
        bf16x8 bf;
        if constexpr (IsFrag<WT>::v) bf = gw(w1, n * 16 + seg * 4 + ss, lane);  // C=512: n*(512/32)
        else                         bf = g8(w1 + (n * 16 + lm) * 512 + seg * 128 + kk);
        acc[n][0] = mfma16(a0, bf, acc[n][0]);
        acc[n][1] = mfma16(a1, bf, acc[n][1]);
      }
    }
  }
#pragma unroll
  for (int n = 0; n < 8; ++n) {
    const float bb = b1[n * 16 + lm];
#pragma unroll
    for (int sub = 0; sub < 2; ++sub)
#pragma unroll
      for (int r = 0; r < 4; ++r) {
        float v = fmaxf(acc[n][sub][r] + bb, 0.f);
        myl[(sub * 16 + quad * 4 + r) * LROW + n * 16 + lm] = (__bf16)v;
      }
  }
  __syncthreads();
  // ---- layer 2 ----
  bf16x8 a20[4], a21[4];
#pragma unroll
  for (int ss = 0; ss < 4; ++ss) {
    a20[ss] = g8(myl + lm * LROW + ss * 32 + quad * 8);
    a21[ss] = g8(myl + (16 + lm) * LROW + ss * 32 + quad * 8);
  }
  f32x4 acc2[8][2] = {};
#pragma unroll
  for (int ss = 0; ss < 4; ++ss) {
    const int kk = ss * 32 + quad * 8;
#pragma unroll
    for (int n = 0; n < 8; ++n) {
      bf16x8 bf;
      if constexpr (IsFrag<WT>::v) bf = gw(w2, n * 4 + ss, lane);  // C=128: n*4
      else                         bf = g8(w2 + (n * 16 + lm) * H + kk);
      acc2[n][0] = mfma16(a20[ss], bf, acc2[n][0]);
      acc2[n][1] = mfma16(a21[ss], bf, acc2[n][1]);
    }
  }
  __syncthreads();
#pragma unroll
  for (int n = 0; n < 8; ++n) {
    const float bb = b2[n * 16 + lm];
#pragma unroll
    for (int sub = 0; sub < 2; ++sub)
#pragma unroll
      for (int r = 0; r < 4; ++r)
        myl[(sub * 16 + quad * 4 + r) * LROW + n * 16 + lm] = (__bf16)(acc2[n][sub][r] + bb);
  }
  __syncthreads();
  // ---- GRU (r/z gates merged i+h accumulators; h-frags carried from seg2) ----
  bf16x8 ao0[4], ao1[4];
#pragma unroll
  for (int ss = 0; ss < 4; ++ss) {
    ao0[ss] = g8(myl + lm * LROW + ss * 32 + quad * 8);
    ao1[ss] = g8(myl + (16 + lm) * LROW + ss * 32 + quad * 8);
  }
#pragma unroll 2
  for (int n = 0; n < 8; ++n) {
    f32x4 ar[2] = {}, az[2] = {}, aig[2] = {}, ahg[2] = {};
#pragma unroll
    for (int ss = 0; ss < 4; ++ss) {
      bf16x8 wr, wz, wg, vr, vz, vg;
      if constexpr (IsFrag<WT>::v) {
        wr = gw(wih, n * 4 + ss, lane);          // gate r: rb=n
        wz = gw(wih, (8 + n) * 4 + ss, lane);    // gate z: rb=8+n
        wg = gw(wih, (16 + n) * 4 + ss, lane);   // gate g: rb=16+n
        vr = gw(whh, n * 4 + ss, lane);
        vz = gw(whh, (8 + n) * 4 + ss, lane);
        vg = gw(whh, (16 + n) * 4 + ss, lane);
      } else {
        const int wr0 = (n * 16 + lm) * H;
        const int kk = ss * 32 + quad * 8;
        wr = g8(wih + wr0 + kk);
        wz = g8(wih + wr0 + 128 * H + kk);
        wg = g8(wih + wr0 + 256 * H + kk);
        vr = g8(whh + wr0 + kk);
        vz = g8(whh + wr0 + 128 * H + kk);
        vg = g8(whh + wr0 + 256 * H + kk);
      }
      ar[0] = mfma16(ao0[ss], wr, ar[0]); ar[0] = mfma16(ah0[ss], vr, ar[0]);
      ar[1] = mfma16(ao1[ss], wr, ar[1]); ar[1] = mfma16(ah1[ss], vr, ar[1]);
      az[0] = mfma16(ao0[ss], wz, az[0]); az[0] = mfma16(ah0[ss], vz, az[0]);
      az[1] = mfma16(ao1[ss], wz, az[1]); az[1] = mfma16(ah1[ss], vz, az[1]);
      aig[0] = mfma16(ao0[ss], wg, aig[0]); aig[1] = mfma16(ao1[ss], wg, aig[1]);
      ahg[0] = mfma16(ah0[ss], vg, ahg[0]); ahg[1] = mfma16(ah1[ss], vg, ahg[1]);
    }
    const int c = n * 16 + lm;
    const float brm = bih[c] + bhh[c];               // merged r bias
    const float bzm = bih[c + 128] + bhh[c + 128];   // merged z bias
    const float big = bih[c + 256], bhg = bhh[c + 256];
#pragma unroll
    for (int sub = 0; sub < 2; ++sub)
#pragma unroll
      for (int r = 0; r < 4; ++r) {
        long epos = base + sub * 16 + quad * 4 + r;
        if (epos < NE) {
          float rg = sigm(ar[sub][r] + brm);
          float zg = sigm(az[sub][r] + bzm);
          float ng = tanh_(aig[sub][r] + big + rg * (ahg[sub][r] + bhg));
          size_t off = (size_t)epos * H + c;
          float hold = ea[off];
          float hnew = (1.f - zg) * ng + zg * hold;
          ea[off] = hnew;
        }
      }
  }
}

// ---------------- node model: MLP(3H->H->H) + GRU ----------------
template <typename WT>
__global__ __launch_bounds__(256, 3) void node_kernel(
    float* __restrict__ x, const WT* __restrict__ xv, __bf16* __restrict__ xbm,
    const WT* __restrict__ uv, const int* __restrict__ batch,
    const WT* __restrict__ aggv, int agg_ok,
    const WT* __restrict__ w1, const float* __restrict__ b1,
    const WT* __restrict__ w2, const float* __restrict__ b2,
    const WT* __restrict__ wih, const WT* __restrict__ whh,
    const float* __restrict__ bih, const float* __restrict__ bhh) {
  __shared__ __bf16 lds[4][32 * LROW];
  const int wave = threadIdx.x >> 6, lane = threadIdx.x & 63;
  const int lm = lane & 15, quad = lane >> 4;
  const long base = ((long)blockIdx.x * 4 + wave) * 32;
  __bf16* myl = lds[wave];

  long tA0 = base + lm;      const int iA0 = (int)(tA0 < NN ? tA0 : NN - 1);
  long tA1 = base + 16 + lm; const int iA1 = (int)(tA1 < NN ? tA1 : NN - 1);
  const int g0 = batch[iA0], g1 = batch[iA1];

  f32x4 acc[8][2] = {};
#pragma unroll
  for (int seg = 0; seg < 3; ++seg) {
#pragma unroll
    for (int ss = 0; ss < 4; ++ss) {
      const int kk = ss * 32 + quad * 8;
      bf16x8 a0, a1;
      if (seg == 0) {
        a0 = g8(xv + (size_t)iA0 * H + kk); a1 = g8(xv + (size_t)iA1 * H + kk);
      } else if (seg == 1) {
        if (agg_ok) { a0 = g8(aggv + (size_t)iA0 * H + kk); a1 = g8(aggv + (size_t)iA1 * H + kk); }
        else        { a0 = zero8(); a1 = zero8(); }
      } else {
        a0 = g8(uv + (size_t)g0 * H + kk); a1 = g8(uv + (size_t)g1 * H + kk);
      }
#pragma unroll
      for (int n = 0; n < 8; ++n) {
        bf16x8 bf;
        if constexpr (IsFrag<WT>::v) bf = gw(w1, n * 12 + seg * 4 + ss, lane);  // C=384: n*12
        else                         bf = g8(w1 + (n * 16 + lm) * 384 + seg * 128 + kk);
        acc[n][0] = mfma16(a0, bf, acc[n][0]);
        acc[n][1] = mfma16(a1, bf, acc[n][1]);
      }
    }
  }
#pragma unroll
  for (int n = 0; n < 8; ++n) {
    const float bb = b1[n * 16 + lm];
#pragma unroll
    for (int sub = 0; sub < 2; ++sub)
#pragma unroll
      for (int r = 0; r < 4; ++r) {
        float v = fmaxf(acc[n][sub][r] + bb, 0.f);
        myl[(sub * 16 + quad * 4 + r) * LROW + n * 16 + lm] = (__bf16)v;
      }
  }
  __syncthreads();
  bf16x8 a20[4], a21[4];
#pragma unroll
  for (int ss = 0; ss < 4; ++ss) {
    a20[ss] = g8(myl + lm * LROW + ss * 32 + quad * 8);
    a21[ss] = g8(myl + (16 + lm) * LROW + ss * 32 + quad * 8);
  }
  f32x4 acc2[8][2] = {};
#pragma unroll
  for (int ss = 0; ss < 4; ++ss) {
    const int kk = ss * 32 + quad * 8;
#pragma unroll
    for (int n = 0; n < 8; ++n) {
      bf16x8 bf;
      if constexpr (IsFrag<WT>::v) bf = gw(w2, n * 4 + ss, lane);
      else                         bf = g8(w2 + (n * 16 + lm) * H + kk);
      acc2[n][0] = mfma16(a20[ss], bf, acc2[n][0]);
      acc2[n][1] = mfma16(a21[ss], bf, acc2[n][1]);
    }
  }
  __syncthreads();
#pragma unroll
  for (int n = 0; n < 8; ++n) {
    const float bb = b2[n * 16 + lm];
#pragma unroll
    for (int sub = 0; sub < 2; ++sub)
#pragma unroll
      for (int r = 0; r < 4; ++r)
        myl[(sub * 16 + quad * 4 + r) * LROW + n * 16 + lm] = (__bf16)(acc2[n][sub][r] + bb);
  }
  __syncthreads();
  bf16x8 ao0[4], ao1[4], ah0[4], ah1[4];
#pragma unroll
  for (int ss = 0; ss < 4; ++ss) {
    const int kk = ss * 32 + quad * 8;
    ao0[ss] = g8(myl + lm * LROW + ss * 32 + quad * 8);
    ao1[ss] = g8(myl + (16 + lm) * LROW + ss * 32 + quad * 8);
    ah0[ss] = g8(xv + (size_t)iA0 * H + kk);
    ah1[ss] = g8(xv + (size_t)iA1 * H + kk);
  }
#pragma unroll 2
  for (int n = 0; n < 8; ++n) {
    f32x4 air[2] = {}, aiz[2] = {}, aig[2] = {};
    f32x4 ahr[2] = {}, ahz[2] = {}, ahg[2] = {};
    const int wr0 = (n * 16 + lm) * H;
#pragma unroll
    for (int ss = 0; ss < 4; ++ss) {
      const int kk = ss * 32 + quad * 8;
      bf16x8 wr, wz, wg, vr, vz, vg;
      if constexpr (IsFrag<WT>::v) {
        wr = gw(wih, n * 4 + ss, lane);
        wz = gw(wih, (8 + n) * 4 + ss, lane);
        wg = gw(wih, (16 + n) * 4 + ss, lane);
        vr = gw(whh, n * 4 + ss, lane);
        vz = gw(whh, (8 + n) * 4 + ss, lane);
        vg = gw(whh, (16 + n) * 4 + ss, lane);
      } else {
        wr = g8(wih + wr0 + kk);
        wz = g8(wih + wr0 + 128 * H + kk);
        wg = g8(wih + wr0 + 256 * H + kk);
        vr = g8(whh + wr0 + kk);
        vz = g8(whh + wr0 + 128 * H + kk);
        vg = g8(whh + wr0 + 256 * H + kk);
      }
      air[0] = mfma16(ao0[ss], wr, air[0]); air[1] = mfma16(ao1[ss], wr, air[1]);
      aiz[0] = mfma16(ao0[ss], wz, aiz[0]); aiz[1] = mfma16(ao1[ss], wz, aiz[1]);
      aig[0] = mfma16(ao0[ss], wg, aig[0]); aig[1] = mfma16(ao1[ss], wg, aig[1]);
      ahr[0] = mfma16(ah0[ss], vr, ahr[0]); ahr[1] = mfma16(ah1[ss], vr, ahr[1]);
      ahz[0] = mfma16(ah0[ss], vz, ahz[0]); ahz[1] = mfma16(ah1[ss], vz, ahz[1]);
      ahg[0] = mfma16(ah0[ss], vg, ahg[0]); ahg[1] = mfma16(ah1[ss], vg, ahg[1]);
    }
    const int c = n * 16 + lm;
    const float bir = bih[c], biz = bih[c + 128], big = bih[c + 256];
    const float bhr = bhh[c], bhz = bhh[c + 128], bhg = bhh[c + 256];
#pragma unroll
    for (int sub = 0; sub < 2; ++sub)
#pragma unroll
      for (int r = 0; r < 4; ++r) {
        long ipos = base + sub * 16 + quad * 4 + r;
        if (ipos < NN) {
          float rg = sigm(air[sub][r] + bir + ahr[sub][r] + bhr);
          float zg = sigm(aiz[sub][r] + biz + ahz[sub][r] + bhz);
          float ng = tanh_(aig[sub][r] + big + rg * (ahg[sub][r] + bhg));
          size_t off = (size_t)ipos * H + c;
          float hold = x[off];
          float hnew = (1.f - zg) * ng + zg * hold;
          x[off] = hnew;
          if (xbm) xbm[off] = (__bf16)hnew;
        }
      }
  }
}

// ---------------- global model: MLP(2H->H->H) + GRU, 1 block ----------------
template <typename WT>
__global__ __launch_bounds__(256) void glob_kernel(
    float* __restrict__ u, const WT* __restrict__ uv, __bf16* __restrict__ ubm,
    const float* __restrict__ xsum, const int* __restrict__ ncnt,
    const WT* __restrict__ w1, const float* __restrict__ b1,
    const WT* __restrict__ w2, const float* __restrict__ b2,
    const WT* __restrict__ wih, const WT* __restrict__ whh,
    const float* __restrict__ bih, const float* __restrict__ bhh,
    float* __restrict__ out, int t, int ws_ok) {
  __shared__ __bf16 lds[4][16 * LROW];
  const int wave = threadIdx.x >> 6, lane = threadIdx.x & 63;
  const int lm = lane & 15, quad = lane >> 4;
  __bf16* myl = lds[wave];
  const int row = wave * 16 + lm;
  const float inv = ws_ok ? 1.f / fmaxf((float)ncnt[row], 1.f) : 1.f;

  f32x4 acc[8] = {};
  bf16x8 ah[4];
#pragma unroll
  for (int seg = 0; seg < 2; ++seg) {
#pragma unroll
    for (int ss = 0; ss < 4; ++ss) {
      const int kk = ss * 32 + quad * 8;
      bf16x8 a;
      if (seg == 0) {
        a = g8(uv + row * H + kk);
        ah[ss] = a;
      } else if (ws_ok) {
        float4 lo = *(const float4*)(xsum + row * H + kk);
        float4 hi = *(const float4*)(xsum + row * H + kk + 4);
        a = cvt8s(lo, hi, inv);
      } else {
        a = zero8();
      }
#pragma unroll
      for (int n = 0; n < 8; ++n) {
        bf16x8 bf;
        if constexpr (IsFrag<WT>::v) bf = gw(w1, n * 8 + seg * 4 + ss, lane);  // C=256: n*8
        else                         bf = g8(w1 + (n * 16 + lm) * 256 + seg * 128 + kk);
        acc[n] = mfma16(a, bf, acc[n]);
      }
    }
  }
#pragma unroll
  for (int n = 0; n < 8; ++n) {
    const float bb = b1[n * 16 + lm];
#pragma unroll
    for (int r = 0; r < 4; ++r)
      myl[(quad * 4 + r) * LROW + n * 16 + lm] = (__bf16)fmaxf(acc[n][r] + bb, 0.f);
  }
  __syncthreads();
  bf16x8 a2[4];
#pragma unroll
  for (int ss = 0; ss < 4; ++ss) a2[ss] = g8(myl + lm * LROW + ss * 32 + quad * 8);
  f32x4 acc2[8] = {};
#pragma unroll
  for (int ss = 0; ss < 4; ++ss) {
    const int kk = ss * 32 + quad * 8;
#pragma unroll
    for (int n = 0; n < 8; ++n) {
      bf16x8 bf;
      if constexpr (IsFrag<WT>::v) bf = gw(w2, n * 4 + ss, lane);
      else                         bf = g8(w2 + (n * 16 + lm) * H + kk);
      acc2[n] = mfma16(a2[ss], bf, acc2[n]);
    }
  }
  __syncthreads();
#pragma unroll
  for (int n = 0; n < 8; ++n) {
    const float bb = b2[n * 16 + lm];
#pragma unroll
    for (int r = 0; r < 4; ++r)
      myl[(quad * 4 + r) * LROW + n * 16 + lm] = (__bf16)(acc2[n][r] + bb);
  }
  __syncthreads();
  bf16x8 ao[4];
#pragma unroll
  for (int ss = 0; ss < 4; ++ss) ao[ss] = g8(myl + lm * LROW + ss * 32 + quad * 8);
  for (int n = 0; n < 8; ++n) {
    f32x4 air = {}, aiz = {}, aig = {}, ahr = {}, ahz = {}, ahg = {};
    const int wr0 = (n * 16 + lm) * H;
#pragma unroll
    for (int ss = 0; ss < 4; ++ss) {
      const int kk = ss * 32 + quad * 8;
      bf16x8 wr, wz, wg, vr, vz, vg;
      if constexpr (IsFrag<WT>::v) {
        wr = gw(wih, n * 4 + ss, lane);
        wz = gw(wih, (8 + n) * 4 + ss, lane);
        wg = gw(wih, (16 + n) * 4 + ss, lane);
        vr = gw(whh, n * 4 + ss, lane);
        vz = gw(whh, (8 + n) * 4 + ss, lane);
        vg = gw(whh, (16 + n) * 4 + ss, lane);
      } else {
        wr = g8(wih + wr0 + kk);
        wz = g8(wih + wr0 + 128 * H + kk);
        wg = g8(wih + wr0 + 256 * H + kk);
        vr = g8(whh + wr0 + kk);
        vz = g8(whh + wr0 + 128 * H + kk);
        vg = g8(whh + wr0 + 256 * H + kk);
      }
      air = mfma16(ao[ss], wr, air);
      aiz = mfma16(ao[ss], wz, aiz);
      aig = mfma16(ao[ss], wg, aig);
      ahr = mfma16(ah[ss], vr, ahr);
      ahz = mfma16(ah[ss], vz, ahz);
      ahg = mfma16(ah[ss], vg, ahg);
    }
    const int c = n * 16 + lm;
    const float bir = bih[c], biz = bih[c + 128], big = bih[c + 256];
    const float bhr = bhh[c], bhz = bhh[c + 128], bhg = bhh[c + 256];
#pragma unroll
    for (int r = 0; r < 4; ++r) {
      const int rowC = wave * 16 + quad * 4 + r;
      float rg = sigm(air[r] + bir + ahr[r] + bhr);
      float zg = sigm(aiz[r] + biz + ahz[r] + bhz);
      float ng = tanh_(aig[r] + big + rg * (ahg[r] + bhg));
      float hold = u[rowC * H + c];
      float hnew = (1.f - zg) * ng + zg * hold;
      u[rowC * H + c] = hnew;
      if (ubm) ubm[rowC * H + c] = (__bf16)hnew;
      out[(rowC * NSTEPS + t) * H + c] = hnew;
    }
  }
}

extern "C" void kernel_launch(void* const* d_in, const int* in_sizes, int n_in,
                              void* d_out, int out_size, void* d_ws, size_t ws_size,
                              hipStream_t stream) {
  float* x = (float*)d_in[0];
  const int* ei = (const int*)d_in[1];
  float* ea = (float*)d_in[2];
  float* u = (float*)d_in[3];
  const int* batch = (const int*)d_in[4];
  float* out = (float*)d_out;

  // ---- workspace layout ----
  char* ws = (char*)d_ws;
  size_t off = 0;
  auto alloc = [&](size_t bytes, size_t align) {
    off = (off + align - 1) & ~(align - 1);
    size_t r = off; off += bytes; return r;
  };
  __bf16* aggb   = (__bf16*)(ws + alloc((size_t)NN * H * 2, 16));
  float*  xsum   = (float*) (ws + alloc((size_t)NB * H * 4, 16));
  int*    dcnt   = (int*)   (ws + alloc((size_t)NN * 4, 4));
  int*    ncnt   = (int*)   (ws + alloc((size_t)NB * 4, 4));   // contiguous w/ dcnt
  int*    rowptr = (int*)   (ws + alloc((size_t)(NN + 1) * 4, 4));
  int*    growptr= (int*)   (ws + alloc((size_t)(NB + 1) * 4, 4));
  int*    fill   = (int*)   (ws + alloc((size_t)NN * 4, 4));
  int*    eids   = (int*)   (ws + alloc((size_t)NE * 4, 4));
  __bf16* wbuf   = (__bf16*)(ws + alloc((size_t)OW_TOTAL * 2, 16));
  __bf16* xb     = (__bf16*)(ws + alloc((size_t)NN * H * 2, 16));
  __bf16* ub     = (__bf16*)(ws + alloc((size_t)NB * H * 2, 16));
  const size_t need_base = off;
  const int ws_ok = (ws_size >= need_base) ? 1 : 0;

  if (ws_ok) {
    W12 w;
    w.p[0] = (const float*)d_in[5];   // ew1
    w.p[1] = (const float*)d_in[7];   // ew2
    w.p[2] = (const float*)d_in[9];   // nw1
    w.p[3] = (const float*)d_in[11];  // nw2
    w.p[4] = (const float*)d_in[13];  // gw1
    w.p[5] = (const float*)d_in[15];  // gw2
    w.p[6] = (const float*)d_in[17];  // ewih
    w.p[7] = (const float*)d_in[18];  // ewhh
    w.p[8] = (const float*)d_in[21];  // nwih
    w.p[9] = (const float*)d_in[22];  // nwhh
    w.p[10] = (const float*)d_in[25]; // gwih
    w.p[11] = (const float*)d_in[26]; // gwhh
    cvt_kernel<<<(OW_TOTAL / 8 + 255) / 256, 256, 0, stream>>>(w, wbuf);
    hipMemsetAsync(dcnt, 0, (NN + NB) * sizeof(int), stream);
    count_kernel<<<(NE + 255) / 256, 256, 0, stream>>>(ei + NE, batch, dcnt, ncnt);
    scan_kernel<<<1, 256, 0, stream>>>(dcnt, ncnt, rowptr, growptr, fill);
    scatter_kernel<<<(NE + 255) / 256, 256, 0, stream>>>(ei + NE, rowptr, fill, eids);
    // activation bf16 mirrors (x, u only — ea stays f32, see R4 post-mortem)
    cvtbuf_kernel<<<((long)NN * H / 8 + 255) / 256, 256, 0, stream>>>(x, xb, (long)NN * H);
    cvtbuf_kernel<<<((long)NB * H / 8 + 255) / 256, 256, 0, stream>>>(u, ub, (long)NB * H);
  }

  for (int t = 0; t < NSTEPS; ++t) {
    if (ws_ok) {
      edge_kernel<__bf16><<<(NE + 127) / 128, 256, 0, stream>>>(
          xb, ei, ea, ub, batch,
          wbuf + OW_EW1, (const float*)d_in[6], wbuf + OW_EW2, (const float*)d_in[8],
          wbuf + OW_EWIH, wbuf + OW_EWHH, (const float*)d_in[19], (const float*)d_in[20]);
      agg_kernel<<<(NN + 3) / 4, 256, 0, stream>>>(ea, rowptr, eids, aggb);
      node_kernel<__bf16><<<(NN + 127) / 128, 256, 0, stream>>>(
          x, xb, xb, ub, batch, aggb, 1,
          wbuf + OW_NW1, (const float*)d_in[10], wbuf + OW_NW2, (const float*)d_in[12],
          wbuf + OW_NWIH, wbuf + OW_NWHH, (const float*)d_in[23], (const float*)d_in[24]);
      xsum_kernel<<<NB, 256, 0, stream>>>(x, growptr, xsum);
      glob_kernel<__bf16><<<1, 256, 0, stream>>>(
          u, ub, ub, xsum, ncnt,
          wbuf + OW_GW1, (const float*)d_in[14], wbuf + OW_GW2, (const float*)d_in[16],
          wbuf + OW_GWIH, wbuf + OW_GWHH, (const float*)d_in[27], (const float*)d_in[28],
          out, t, 1);
    } else {
      // never-taken safety path: raw f32 weights/activations (row-major), no workspace
      edge_kernel<float><<<(NE + 127) / 128, 256, 0, stream>>>(
          x, ei, ea, u, batch,
          (const float*)d_in[5], (const float*)d_in[6], (const float*)d_in[7], (const float*)d_in[8],
          (const float*)d_in[17], (const float*)d_in[18], (const float*)d_in[19], (const float*)d_in[20]);
      node_kernel<float><<<(NN + 127) / 128, 256, 0, stream>>>(
          x, x, nullptr, u, batch, nullptr, 0,
          (const float*)d_in[9], (const float*)d_in[10], (const float*)d_in[11], (const float*)d_in[12],
          (const float*)d_in[21], (const float*)d_in[22], (const float*)d_in[23], (const float*)d_in[24]);
      glob_kernel<float><<<1, 256, 0, stream>>>(
          u, u, nullptr, xsum, ncnt,
          (const float*)d_in[13], (const float*)d_in[14], (const float*)d_in[15], (const float*)d_in[16],
          (const float*)d_in[25], (const float*)d_in[26], (const float*)d_in[27], (const float*)d_in[28],
          out, t, 0);
    }
  }
}

// Round 17
// 3194.793 us; speedup vs baseline: 1.0561x; 1.0023x over previous
//
#include <hip/hip_runtime.h>
#include <hip/hip_bf16.h>

#define H 128
#define NN 50000
#define NE 500000
#define NB 64
#define NSTEPS 3
#define LROW 136  // 128 + 8 pad
#define STRIP ((NN + 255) / 256)

// LDS in the MFMA kernels is wave-private (myl = lds[wave]); cross-wave sync is
// unnecessary. Replace __syncthreads (which drains vmcnt(0) — kills the weight-load
// pipeline) with a zero-cost compiler reorder fence. Cross-lane LDS visibility
// within a wave is guaranteed by in-order per-wave ds ops + compiler lgkmcnt waits.
#if defined(__has_builtin)
#if __has_builtin(__builtin_amdgcn_wave_barrier)
#define WAVE_FENCE() __builtin_amdgcn_wave_barrier()
#else
#define WAVE_FENCE() asm volatile("" ::: "memory")
#endif
#else
#define WAVE_FENCE() asm volatile("" ::: "memory")
#endif

typedef __bf16 bf16x8 __attribute__((ext_vector_type(8)));
typedef __bf16 bf16x2 __attribute__((ext_vector_type(2)));
typedef float f32x4 __attribute__((ext_vector_type(4)));

// frag-layout trait: bf16 staged weights use fragment-major layout; f32 fallback = row-major
template <typename T> struct IsFrag { static constexpr bool v = false; };
template <> struct IsFrag<__bf16> { static constexpr bool v = true; };

__device__ __forceinline__ f32x4 mfma16(bf16x8 a, bf16x8 b, f32x4 c) {
  return __builtin_amdgcn_mfma_f32_16x16x32_bf16(a, b, c, 0, 0, 0);
}
__device__ __forceinline__ float sigm(float x) { return 1.f / (1.f + __expf(-x)); }
__device__ __forceinline__ float tanh_(float x) { return 1.f - 2.f / (1.f + __expf(2.f * x)); }
__device__ __forceinline__ bf16x8 cvt8s(float4 lo, float4 hi, float s) {
  bf16x8 v;
  v[0] = (__bf16)(lo.x * s); v[1] = (__bf16)(lo.y * s);
  v[2] = (__bf16)(lo.z * s); v[3] = (__bf16)(lo.w * s);
  v[4] = (__bf16)(hi.x * s); v[5] = (__bf16)(hi.y * s);
  v[6] = (__bf16)(hi.z * s); v[7] = (__bf16)(hi.w * s);
  return v;
}
__device__ __forceinline__ bf16x8 g8(const __bf16* p) { return *reinterpret_cast<const bf16x8*>(p); }
__device__ __forceinline__ bf16x8 g8(const float* p) {
  float4 lo = *(const float4*)p, hi = *(const float4*)(p + 4);
  return cvt8s(lo, hi, 1.f);
}
__device__ __forceinline__ bf16x8 zero8() {
  bf16x8 v;
#pragma unroll
  for (int i = 0; i < 8; ++i) v[i] = (__bf16)0.f;
  return v;
}
// fragment-major weight load: fragment group fg = rb*(C/32)+cb, lane-contiguous 16B
__device__ __forceinline__ bf16x8 gw(const __bf16* w, int fg, int lane) {
  return *reinterpret_cast<const bf16x8*>(w + ((size_t)fg * 64 + lane) * 8);
}

// ---------------- weight staging: 12 f32 matrices -> bf16 frag-major in ws ----------------
#define OW_EW1 0
#define OW_EW2 65536
#define OW_NW1 81920
#define OW_NW2 131072
#define OW_GW1 147456
#define OW_GW2 180224
#define OW_EWIH 196608
#define OW_EWHH 245760
#define OW_NWIH 294912
#define OW_NWHH 344064
#define OW_GWIH 393216
#define OW_GWHH 442368
#define OW_TOTAL 491520

struct W12 { const float* p[12]; };

// frag-major reorder: dest elem o in matrix s:
//   fg = o/512, lane = (o/8)%64, e = o%8
//   rb = fg/(C/32), cb = fg%(C/32)
//   src (r,c) = (rb*16 + (lane&15), cb*32 + (lane>>4)*8 + e)
__global__ __launch_bounds__(256) void cvt_kernel(W12 w, __bf16* __restrict__ out) {
  const int off[13] = {OW_EW1, OW_EW2, OW_NW1, OW_NW2, OW_GW1, OW_GW2,
                       OW_EWIH, OW_EWHH, OW_NWIH, OW_NWHH, OW_GWIH, OW_GWHH, OW_TOTAL};
  const int Cs[12] = {512, 128, 384, 128, 256, 128, 128, 128, 128, 128, 128, 128};
  int e = (blockIdx.x * 256 + threadIdx.x) * 8;
  if (e >= OW_TOTAL) return;
  int s = 0;
#pragma unroll
  for (int i = 1; i < 12; ++i)
    if (e >= off[i]) s = i;
  const int C = Cs[s];
  const int local = e - off[s];
  const int fg = local >> 9;           // /512
  const int lane = (local >> 3) & 63;  // lane within fragment group
  const int nb = C >> 5;               // C/32
  const int rb = fg / nb, cb = fg - rb * nb;
  const int r = rb * 16 + (lane & 15);
  const int c = cb * 32 + (lane >> 4) * 8;
  const float* src = w.p[s] + (size_t)r * C + c;
  float4 lo = *(const float4*)src, hi = *(const float4*)(src + 4);
  *reinterpret_cast<bf16x8*>(out + e) = cvt8s(lo, hi, 1.f);
}

// generic f32 -> bf16 buffer mirror (counts divisible by 8)
__global__ __launch_bounds__(256) void cvtbuf_kernel(const float* __restrict__ src,
                                                     __bf16* __restrict__ dst, long n) {
  long i = ((long)blockIdx.x * 256 + threadIdx.x) * 8;
  if (i >= n) return;
  float4 lo = *(const float4*)(src + i), hi = *(const float4*)(src + i + 4);
  *reinterpret_cast<bf16x8*>(dst + i) = cvt8s(lo, hi, 1.f);
}

__global__ void count_kernel(const int* __restrict__ dst, const int* __restrict__ batch,
                             int* __restrict__ dcnt, int* __restrict__ ncnt) {
  int i = blockIdx.x * 256 + threadIdx.x;
  if (i < NE) atomicAdd(&dcnt[dst[i]], 1);
  if (i < NN) atomicAdd(&ncnt[batch[i]], 1);
}

// ---------------- CSR build (once; graph static across steps) ----------------
__global__ __launch_bounds__(256) void scan_kernel(const int* __restrict__ dcnt,
                                                   const int* __restrict__ ncnt,
                                                   int* __restrict__ rowptr,   // NN+1
                                                   int* __restrict__ growptr,  // NB+1
                                                   int* __restrict__ fill) {
  __shared__ int ssum[256];
  const int t = threadIdx.x;
  const int b0 = t * STRIP;
  const int b1 = min(b0 + STRIP, NN);
  int s = 0;
  for (int i = b0; i < b1; ++i) s += dcnt[i];
  ssum[t] = s;
  __syncthreads();
  if (t == 0) {
    int run = 0;
    for (int i = 0; i < 256; ++i) { int v = ssum[i]; ssum[i] = run; run += v; }
  }
  __syncthreads();
  int off = ssum[t];
  for (int i = b0; i < b1; ++i) { rowptr[i] = off; off += dcnt[i]; fill[i] = 0; }
  if (b1 == NN) rowptr[NN] = off;
  if (t == 0) {
    int run = 0;
    for (int g = 0; g < NB; ++g) { growptr[g] = run; run += ncnt[g]; }
    growptr[NB] = run;
  }
}

__global__ __launch_bounds__(256) void scatter_kernel(const int* __restrict__ dst,
                                                      const int* __restrict__ rowptr,
                                                      int* __restrict__ fill,
                                                      int* __restrict__ eids) {
  int i = blockIdx.x * 256 + threadIdx.x;
  if (i >= NE) return;
  int d = dst[i];
  int pos = rowptr[d] + atomicAdd(&fill[d], 1);
  eids[pos] = i;
}

// -------- per-step gather aggregation: aggb[v] = bf16(mean(ea[in-edges])) ----
__global__ __launch_bounds__(256) void agg_kernel(const float* __restrict__ ea,
                                                  const int* __restrict__ rowptr,
                                                  const int* __restrict__ eids,
                                                  __bf16* __restrict__ aggb) {
  const int wave = threadIdx.x >> 6, lane = threadIdx.x & 63;
  const int v = blockIdx.x * 4 + wave;
  if (v >= NN) return;
  const int beg = rowptr[v], end = rowptr[v + 1];
  const int deg = end - beg;
  float ax = 0.f, ay = 0.f;
  for (int base = beg; base < end; base += 64) {
    const int nb = min(64, end - base);
    const int le = (base + lane < end) ? eids[base + lane] : 0;
#pragma unroll 4
    for (int e = 0; e < nb; ++e) {
      const int eid = __shfl(le, e, 64);
      const float2 val = *reinterpret_cast<const float2*>(ea + (size_t)eid * H + lane * 2);
      ax += val.x; ay += val.y;
    }
  }
  const float inv = 1.f / (float)max(deg, 1);
  bf16x2 o;
  o[0] = (__bf16)(ax * inv);
  o[1] = (__bf16)(ay * inv);
  *reinterpret_cast<bf16x2*>(aggb + (size_t)v * H + lane * 2) = o;
}

// ---------------- per-step per-graph node sum (batch sorted) -----------------
__global__ __launch_bounds__(256) void xsum_kernel(const float* __restrict__ x,
                                                   const int* __restrict__ growptr,
                                                   float* __restrict__ xsum) {
  __shared__ float part[256];
  const int g = blockIdx.x;
  const int t = threadIdx.x;
  const int col = t & 127, half = t >> 7;
  const int beg = growptr[g], end = growptr[g + 1];
  float s = 0.f;
  for (int r = beg + half; r < end; r += 2) s += x[(size_t)r * H + col];
  part[t] = s;
  __syncthreads();
  if (half == 0) xsum[g * H + col] = part[col] + part[128 + col];
}

// -------- edge model: MLP(4H->H->H) + GRU, per-wave M=32, ea-frag carry ------
template <typename WT>
__global__ __launch_bounds__(256, 3) void edge_kernel(
    const WT* __restrict__ xv, const int* __restrict__ ei,
    float* __restrict__ ea,
    const WT* __restrict__ uv, const int* __restrict__ batch,
    const WT* __restrict__ w1, const float* __restrict__ b1,
    const WT* __restrict__ w2, const float* __restrict__ b2,
    const WT* __restrict__ wih, const WT* __restrict__ whh,
    const float* __restrict__ bih, const float* __restrict__ bhh) {
  __shared__ __bf16 lds[4][32 * LROW];
  const int* src = ei;
  const int* dst = ei + NE;
  const int wave = threadIdx.x >> 6, lane = threadIdx.x & 63;
  const int lm = lane & 15, quad = lane >> 4;
  const long base = ((long)blockIdx.x * 4 + wave) * 32;
  __bf16* myl = lds[wave];

  long tA0 = base + lm;      const int eA0 = (int)(tA0 < NE ? tA0 : NE - 1);
  long tA1 = base + 16 + lm; const int eA1 = (int)(tA1 < NE ? tA1 : NE - 1);
  const int s0 = src[eA0], s1 = src[eA1];
  const int d0 = dst[eA0], d1 = dst[eA1];
  const int g0 = batch[s0], g1 = batch[s1];

  // ---- layer 1: K = 512 over 4 gathered segments; carry ea frags to GRU ----
  f32x4 acc[8][2] = {};
  bf16x8 ah0[4], ah1[4];   // seg2 ea fragments, reused by GRU h-path (no reload)
#pragma unroll
  for (int seg = 0; seg < 4; ++seg) {
#pragma unroll
    for (int ss = 0; ss < 4; ++ss) {
      const int kk = ss * 32 + quad * 8;
      bf16x8 a0, a1;
      if (seg == 0) {
        a0 = g8(xv + (size_t)s0 * H + kk); a1 = g8(xv + (size_t)s1 * H + kk);
      } else if (seg == 1) {
        a0 = g8(xv + (size_t)d0 * H + kk); a1 = g8(xv + (size_t)d1 * H + kk);
      } else if (seg == 2) {
        a0 = g8(ea + (size_t)eA0 * H + kk); a1 = g8(ea + (size_t)eA1 * H + kk);
        ah0[ss] = a0; ah1[ss] = a1;
      } else {
        a0 = g8(uv + (size_t)g0 * H + kk); a1 = g8(uv + (size_t)g1 * H + kk);
      }
#pragma unroll
      for (int n = 0; n < 8; ++n) {
        bf16x8 bf;
        if constexpr (IsFrag<WT>::v) bf = gw(w1, n * 16 + seg * 4 + ss, lane);  // C=512: n*(512/32)
        else                         bf = g8(w1 + (n * 16 + lm) * 512 + seg * 128 + kk);
        acc[n][0] = mfma16(a0, bf, acc[n][0]);
        acc[n][1] = mfma16(a1, bf, acc[n][1]);
      }
    }
  }
#pragma unroll
  for (int n = 0; n < 8; ++n) {
    const float bb = b1[n * 16 + lm];
#pragma unroll
    for (int sub = 0; sub < 2; ++sub)
#pragma unroll
      for (int r = 0; r < 4; ++r) {
        float v = fmaxf(acc[n][sub][r] + bb, 0.f);
        myl[(sub * 16 + quad * 4 + r) * LROW + n * 16 + lm] = (__bf16)v;
      }
  }
  WAVE_FENCE();   // LDS is wave-private: no cross-wave barrier, no vmcnt drain
  // ---- layer 2 ----
  bf16x8 a20[4], a21[4];
#pragma unroll
  for (int ss = 0; ss < 4; ++ss) {
    a20[ss] = g8(myl + lm * LROW + ss * 32 + quad * 8);
    a21[ss] = g8(myl + (16 + lm) * LROW + ss * 32 + quad * 8);
  }
  f32x4 acc2[8][2] = {};
#pragma unroll
  for (int ss = 0; ss < 4; ++ss) {
    const int kk = ss * 32 + quad * 8;
#pragma unroll
    for (int n = 0; n < 8; ++n) {
      bf16x8 bf;
      if constexpr (IsFrag<WT>::v) bf = gw(w2, n * 4 + ss, lane);  // C=128: n*4
      else                         bf = g8(w2 + (n * 16 + lm) * H + kk);
      acc2[n][0] = mfma16(a20[ss], bf, acc2[n][0]);
      acc2[n][1] = mfma16(a21[ss], bf, acc2[n][1]);
    }
  }
  WAVE_FENCE();
#pragma unroll
  for (int n = 0; n < 8; ++n) {
    const float bb = b2[n * 16 + lm];
#pragma unroll
    for (int sub = 0; sub < 2; ++sub)
#pragma unroll
      for (int r = 0; r < 4; ++r)
        myl[(sub * 16 + quad * 4 + r) * LROW + n * 16 + lm] = (__bf16)(acc2[n][sub][r] + bb);
  }
  WAVE_FENCE();
  // ---- GRU (r/z gates merged i+h accumulators; h-frags carried from seg2) ----
  bf16x8 ao0[4], ao1[4];
#pragma unroll
  for (int ss = 0; ss < 4; ++ss) {
    ao0[ss] = g8(myl + lm * LROW + ss * 32 + quad * 8);
    ao1[ss] = g8(myl + (16 + lm) * LROW + ss * 32 + quad * 8);
  }
#pragma unroll 2
  for (int n = 0; n < 8; ++n) {
    f32x4 ar[2] = {}, az[2] = {}, aig[2] = {}, ahg[2] = {};
#pragma unroll
    for (int ss = 0; ss < 4; ++ss) {
      bf16x8 wr, wz, wg, vr, vz, vg;
      if constexpr (IsFrag<WT>::v) {
        wr = gw(wih, n * 4 + ss, lane);          // gate r: rb=n
        wz = gw(wih, (8 + n) * 4 + ss, lane);    // gate z: rb=8+n
        wg = gw(wih, (16 + n) * 4 + ss, lane);   // gate g: rb=16+n
        vr = gw(whh, n * 4 + ss, lane);
        vz = gw(whh, (8 + n) * 4 + ss, lane);
        vg = gw(whh, (16 + n) * 4 + ss, lane);
      } else {
        const int wr0 = (n * 16 + lm) * H;
        const int kk = ss * 32 + quad * 8;
        wr = g8(wih + wr0 + kk);
        wz = g8(wih + wr0 + 128 * H + kk);
        wg = g8(wih + wr0 + 256 * H + kk);
        vr = g8(whh + wr0 + kk);
        vz = g8(whh + wr0 + 128 * H + kk);
        vg = g8(whh + wr0 + 256 * H + kk);
      }
      ar[0] = mfma16(ao0[ss], wr, ar[0]); ar[0] = mfma16(ah0[ss], vr, ar[0]);
      ar[1] = mfma16(ao1[ss], wr, ar[1]); ar[1] = mfma16(ah1[ss], vr, ar[1]);
      az[0] = mfma16(ao0[ss], wz, az[0]); az[0] = mfma16(ah0[ss], vz, az[0]);
      az[1] = mfma16(ao1[ss], wz, az[1]); az[1] = mfma16(ah1[ss], vz, az[1]);
      aig[0] = mfma16(ao0[ss], wg, aig[0]); aig[1] = mfma16(ao1[ss], wg, aig[1]);
      ahg[0] = mfma16(ah0[ss], vg, ahg[0]); ahg[1] = mfma16(ah1[ss], vg, ahg[1]);
    }
    const int c = n * 16 + lm;
    const float brm = bih[c] + bhh[c];               // merged r bias
    const float bzm = bih[c + 128] + bhh[c + 128];   // merged z bias
    const float big = bih[c + 256], bhg = bhh[c + 256];
#pragma unroll
    for (int sub = 0; sub < 2; ++sub)
#pragma unroll
      for (int r = 0; r < 4; ++r) {
        long epos = base + sub * 16 + quad * 4 + r;
        if (epos < NE) {
          float rg = sigm(ar[sub][r] + brm);
          float zg = sigm(az[sub][r] + bzm);
          float ng = tanh_(aig[sub][r] + big + rg * (ahg[sub][r] + bhg));
          size_t off = (size_t)epos * H + c;
          float hold = ea[off];
          float hnew = (1.f - zg) * ng + zg * hold;
          ea[off] = hnew;
        }
      }
  }
}

// ---------------- node model: MLP(3H->H->H) + GRU ----------------
template <typename WT>
__global__ __launch_bounds__(256, 3) void node_kernel(
    float* __restrict__ x, const WT* __restrict__ xv, __bf16* __restrict__ xbm,
    const WT* __restrict__ uv, const int* __restrict__ batch,
    const WT* __restrict__ aggv, int agg_ok,
    const WT* __restrict__ w1, const float* __restrict__ b1,
    const WT* __restrict__ w2, const float* __restrict__ b2,
    const WT* __restrict__ wih, const WT* __restrict__ whh,
    const float* __restrict__ bih, const float* __restrict__ bhh) {
  __shared__ __bf16 lds[4][32 * LROW];
  const int wave = threadIdx.x >> 6, lane = threadIdx.x & 63;
  const int lm = lane & 15, quad = lane >> 4;
  const long base = ((long)blockIdx.x * 4 + wave) * 32;
  __bf16* myl = lds[wave];

  long tA0 = base + lm;      const int iA0 = (int)(tA0 < NN ? tA0 : NN - 1);
  long tA1 = base + 16 + lm; const int iA1 = (int)(tA1 < NN ? tA1 : NN - 1);
  const int g0 = batch[iA0], g1 = batch[iA1];

  f32x4 acc[8][2] = {};
#pragma unroll
  for (int seg = 0; seg < 3; ++seg) {
#pragma unroll
    for (int ss = 0; ss < 4; ++ss) {
      const int kk = ss * 32 + quad * 8;
      bf16x8 a0, a1;
      if (seg == 0) {
        a0 = g8(xv + (size_t)iA0 * H + kk); a1 = g8(xv + (size_t)iA1 * H + kk);
      } else if (seg == 1) {
        if (agg_ok) { a0 = g8(aggv + (size_t)iA0 * H + kk); a1 = g8(aggv + (size_t)iA1 * H + kk); }
        else        { a0 = zero8(); a1 = zero8(); }
      } else {
        a0 = g8(uv + (size_t)g0 * H + kk); a1 = g8(uv + (size_t)g1 * H + kk);
      }
#pragma unroll
      for (int n = 0; n < 8; ++n) {
        bf16x8 bf;
        if constexpr (IsFrag<WT>::v) bf = gw(w1, n * 12 + seg * 4 + ss, lane);  // C=384: n*12
        else                         bf = g8(w1 + (n * 16 + lm) * 384 + seg * 128 + kk);
        acc[n][0] = mfma16(a0, bf, acc[n][0]);
        acc[n][1] = mfma16(a1, bf, acc[n][1]);
      }
    }
  }
#pragma unroll
  for (int n = 0; n < 8; ++n) {
    const float bb = b1[n * 16 + lm];
#pragma unroll
    for (int sub = 0; sub < 2; ++sub)
#pragma unroll
      for (int r = 0; r < 4; ++r) {
        float v = fmaxf(acc[n][sub][r] + bb, 0.f);
        myl[(sub * 16 + quad * 4 + r) * LROW + n * 16 + lm] = (__bf16)v;
      }
  }
  WAVE_FENCE();
  bf16x8 a20[4], a21[4];
#pragma unroll
  for (int ss = 0; ss < 4; ++ss) {
    a20[ss] = g8(myl + lm * LROW + ss * 32 + quad * 8);
    a21[ss] = g8(myl + (16 + lm) * LROW + ss * 32 + quad * 8);
  }
  f32x4 acc2[8][2] = {};
#pragma unroll
  for (int ss = 0; ss < 4; ++ss) {
    const int kk = ss * 32 + quad * 8;
#pragma unroll
    for (int n = 0; n < 8; ++n) {
      bf16x8 bf;
      if constexpr (IsFrag<WT>::v) bf = gw(w2, n * 4 + ss, lane);
      else                         bf = g8(w2 + (n * 16 + lm) * H + kk);
      acc2[n][0] = mfma16(a20[ss], bf, acc2[n][0]);
      acc2[n][1] = mfma16(a21[ss], bf, acc2[n][1]);
    }
  }
  WAVE_FENCE();
#pragma unroll
  for (int n = 0; n < 8; ++n) {
    const float bb = b2[n * 16 + lm];
#pragma unroll
    for (int sub = 0; sub < 2; ++sub)
#pragma unroll
      for (int r = 0; r < 4; ++r)
        myl[(sub * 16 + quad * 4 + r) * LROW + n * 16 + lm] = (__bf16)(acc2[n][sub][r] + bb);
  }
  WAVE_FENCE();
  bf16x8 ao0[4], ao1[4], ah0[4], ah1[4];
#pragma unroll
  for (int ss = 0; ss < 4; ++ss) {
    const int kk = ss * 32 + quad * 8;
    ao0[ss] = g8(myl + lm * LROW + ss * 32 + quad * 8);
    ao1[ss] = g8(myl + (16 + lm) * LROW + ss * 32 + quad * 8);
    ah0[ss] = g8(xv + (size_t)iA0 * H + kk);
    ah1[ss] = g8(xv + (size_t)iA1 * H + kk);
  }
#pragma unroll 2
  for (int n = 0; n < 8; ++n) {
    f32x4 air[2] = {}, aiz[2] = {}, aig[2] = {};
    f32x4 ahr[2] = {}, ahz[2] = {}, ahg[2] = {};
    const int wr0 = (n * 16 + lm) * H;
#pragma unroll
    for (int ss = 0; ss < 4; ++ss) {
      const int kk = ss * 32 + quad * 8;
      bf16x8 wr, wz, wg, vr, vz, vg;
      if constexpr (IsFrag<WT>::v) {
        wr = gw(wih, n * 4 + ss, lane);
        wz = gw(wih, (8 + n) * 4 + ss, lane);
        wg = gw(wih, (16 + n) * 4 + ss, lane);
        vr = gw(whh, n * 4 + ss, lane);
        vz = gw(whh, (8 + n) * 4 + ss, lane);
        vg = gw(whh, (16 + n) * 4 + ss, lane);
      } else {
        wr = g8(wih + wr0 + kk);
        wz = g8(wih + wr0 + 128 * H + kk);
        wg = g8(wih + wr0 + 256 * H + kk);
        vr = g8(whh + wr0 + kk);
        vz = g8(whh + wr0 + 128 * H + kk);
        vg = g8(whh + wr0 + 256 * H + kk);
      }
      air[0] = mfma16(ao0[ss], wr, air[0]); air[1] = mfma16(ao1[ss], wr, air[1]);
      aiz[0] = mfma16(ao0[ss], wz, aiz[0]); aiz[1] = mfma16(ao1[ss], wz, aiz[1]);
      aig[0] = mfma16(ao0[ss], wg, aig[0]); aig[1] = mfma16(ao1[ss], wg, aig[1]);
      ahr[0] = mfma16(ah0[ss], vr, ahr[0]); ahr[1] = mfma16(ah1[ss], vr, ahr[1]);
      ahz[0] = mfma16(ah0[ss], vz, ahz[0]); ahz[1] = mfma16(ah1[ss], vz, ahz[1]);
      ahg[0] = mfma16(ah0[ss], vg, ahg[0]); ahg[1] = mfma16(ah1[ss], vg, ahg[1]);
    }
    const int c = n * 16 + lm;
    const float bir = bih[c], biz = bih[c + 128], big = bih[c + 256];
    const float bhr = bhh[c], bhz = bhh[c + 128], bhg = bhh[c + 256];
#pragma unroll
    for (int sub = 0; sub < 2; ++sub)
#pragma unroll
      for (int r = 0; r < 4; ++r) {
        long ipos = base + sub * 16 + quad * 4 + r;
        if (ipos < NN) {
          float rg = sigm(air[sub][r] + bir + ahr[sub][r] + bhr);
          float zg = sigm(aiz[sub][r] + biz + ahz[sub][r] + bhz);
          float ng = tanh_(aig[sub][r] + big + rg * (ahg[sub][r] + bhg));
          size_t off = (size_t)ipos * H + c;
          float hold = x[off];
          float hnew = (1.f - zg) * ng + zg * hold;
          x[off] = hnew;
          if (xbm) xbm[off] = (__bf16)hnew;
        }
      }
  }
}

// ---------------- global model: MLP(2H->H->H) + GRU, 1 block ----------------
template <typename WT>
__global__ __launch_bounds__(256) void glob_kernel(
    float* __restrict__ u, const WT* __restrict__ uv, __bf16* __restrict__ ubm,
    const float* __restrict__ xsum, const int* __restrict__ ncnt,
    const WT* __restrict__ w1, const float* __restrict__ b1,
    const WT* __restrict__ w2, const float* __restrict__ b2,
    const WT* __restrict__ wih, const WT* __restrict__ whh,
    const float* __restrict__ bih, const float* __restrict__ bhh,
    float* __restrict__ out, int t, int ws_ok) {
  __shared__ __bf16 lds[4][16 * LROW];
  const int wave = threadIdx.x >> 6, lane = threadIdx.x & 63;
  const int lm = lane & 15, quad = lane >> 4;
  __bf16* myl = lds[wave];
  const int row = wave * 16 + lm;
  const float inv = ws_ok ? 1.f / fmaxf((float)ncnt[row], 1.f) : 1.f;

  f32x4 acc[8] = {};
  bf16x8 ah[4];
#pragma unroll
  for (int seg = 0; seg < 2; ++seg) {
#pragma unroll
    for (int ss = 0; ss < 4; ++ss) {
      const int kk = ss * 32 + quad * 8;
      bf16x8 a;
      if (seg == 0) {
        a = g8(uv + row * H + kk);
        ah[ss] = a;
      } else if (ws_ok) {
        float4 lo = *(const float4*)(xsum + row * H + kk);
        float4 hi = *(const float4*)(xsum + row * H + kk + 4);
        a = cvt8s(lo, hi, inv);
      } else {
        a = zero8();
      }
#pragma unroll
      for (int n = 0; n < 8; ++n) {
        bf16x8 bf;
        if constexpr (IsFrag<WT>::v) bf = gw(w1, n * 8 + seg * 4 + ss, lane);  // C=256: n*8
        else                         bf = g8(w1 + (n * 16 + lm) * 256 + seg * 128 + kk);
        acc[n] = mfma16(a, bf, acc[n]);
      }
    }
  }
#pragma unroll
  for (int n = 0; n < 8; ++n) {
    const float bb = b1[n * 16 + lm];
#pragma unroll
    for (int r = 0; r < 4; ++r)
      myl[(quad * 4 + r) * LROW + n * 16 + lm] = (__bf16)fmaxf(acc[n][r] + bb, 0.f);
  }
  WAVE_FENCE();
  bf16x8 a2[4];
#pragma unroll
  for (int ss = 0; ss < 4; ++ss) a2[ss] = g8(myl + lm * LROW + ss * 32 + quad * 8);
  f32x4 acc2[8] = {};
#pragma unroll
  for (int ss = 0; ss < 4; ++ss) {
    const int kk = ss * 32 + quad * 8;
#pragma unroll
    for (int n = 0; n < 8; ++n) {
      bf16x8 bf;
      if constexpr (IsFrag<WT>::v) bf = gw(w2, n * 4 + ss, lane);
      else                         bf = g8(w2 + (n * 16 + lm) * H + kk);
      acc2[n] = mfma16(a2[ss], bf, acc2[n]);
    }
  }
  WAVE_FENCE();
#pragma unroll
  for (int n = 0; n < 8; ++n) {
    const float bb = b2[n * 16 + lm];
#pragma unroll
    for (int r = 0; r < 4; ++r)
      myl[(quad * 4 + r) * LROW + n * 16 + lm] = (__bf16)(acc2[n][r] + bb);
  }
  WAVE_FENCE();
  bf16x8 ao[4];
#pragma unroll
  for (int ss = 0; ss < 4; ++ss) ao[ss] = g8(myl + lm * LROW + ss * 32 + quad * 8);
  for (int n = 0; n < 8; ++n) {
    f32x4 air = {}, aiz = {}, aig = {}, ahr = {}, ahz = {}, ahg = {};
    const int wr0 = (n * 16 + lm) * H;
#pragma unroll
    for (int ss = 0; ss < 4; ++ss) {
      const int kk = ss * 32 + quad * 8;
      bf16x8 wr, wz, wg, vr, vz, vg;
      if constexpr (IsFrag<WT>::v) {
        wr = gw(wih, n * 4 + ss, lane);
        wz = gw(wih, (8 + n) * 4 + ss, lane);
        wg = gw(wih, (16 + n) * 4 + ss, lane);
        vr = gw(whh, n * 4 + ss, lane);
        vz = gw(whh, (8 + n) * 4 + ss, lane);
        vg = gw(whh, (16 + n) * 4 + ss, lane);
      } else {
        wr = g8(wih + wr0 + kk);
        wz = g8(wih + wr0 + 128 * H + kk);
        wg = g8(wih + wr0 + 256 * H + kk);
        vr = g8(whh + wr0 + kk);
        vz = g8(whh + wr0 + 128 * H + kk);
        vg = g8(whh + wr0 + 256 * H + kk);
      }
      air = mfma16(ao[ss], wr, air);
      aiz = mfma16(ao[ss], wz, aiz);
      aig = mfma16(ao[ss], wg, aig);
      ahr = mfma16(ah[ss], vr, ahr);
      ahz = mfma16(ah[ss], vz, ahz);
      ahg = mfma16(ah[ss], vg, ahg);
    }
    const int c = n * 16 + lm;
    const float bir = bih[c], biz = bih[c + 128], big = bih[c + 256];
    const float bhr = bhh[c], bhz = bhh[c + 128], bhg = bhh[c + 256];
#pragma unroll
    for (int r = 0; r < 4; ++r) {
      const int rowC = wave * 16 + quad * 4 + r;
      float rg = sigm(air[r] + bir + ahr[r] + bhr);
      float zg = sigm(aiz[r] + biz + ahz[r] + bhz);
      float ng = tanh_(aig[r] + big + rg * (ahg[r] + bhg));
      float hold = u[rowC * H + c];
      float hnew = (1.f - zg) * ng + zg * hold;
      u[rowC * H + c] = hnew;
      if (ubm) ubm[rowC * H + c] = (__bf16)hnew;
      out[(rowC * NSTEPS + t) * H + c] = hnew;
    }
  }
}

extern "C" void kernel_launch(void* const* d_in, const int* in_sizes, int n_in,
                              void* d_out, int out_size, void* d_ws, size_t ws_size,
                              hipStream_t stream) {
  float* x = (float*)d_in[0];
  const int* ei = (const int*)d_in[1];
  float* ea = (float*)d_in[2];
  float* u = (float*)d_in[3];
  const int* batch = (const int*)d_in[4];
  float* out = (float*)d_out;

  // ---- workspace layout ----
  char* ws = (char*)d_ws;
  size_t off = 0;
  auto alloc = [&](size_t bytes, size_t align) {
    off = (off + align - 1) & ~(align - 1);
    size_t r = off; off += bytes; return r;
  };
  __bf16* aggb   = (__bf16*)(ws + alloc((size_t)NN * H * 2, 16));
  float*  xsum   = (float*) (ws + alloc((size_t)NB * H * 4, 16));
  int*    dcnt   = (int*)   (ws + alloc((size_t)NN * 4, 4));
  int*    ncnt   = (int*)   (ws + alloc((size_t)NB * 4, 4));   // contiguous w/ dcnt
  int*    rowptr = (int*)   (ws + alloc((size_t)(NN + 1) * 4, 4));
  int*    growptr= (int*)   (ws + alloc((size_t)(NB + 1) * 4, 4));
  int*    fill   = (int*)   (ws + alloc((size_t)NN * 4, 4));
  int*    eids   = (int*)   (ws + alloc((size_t)NE * 4, 4));
  __bf16* wbuf   = (__bf16*)(ws + alloc((size_t)OW_TOTAL * 2, 16));
  __bf16* xb     = (__bf16*)(ws + alloc((size_t)NN * H * 2, 16));
  __bf16* ub     = (__bf16*)(ws + alloc((size_t)NB * H * 2, 16));
  const size_t need_base = off;
  const int ws_ok = (ws_size >= need_base) ? 1 : 0;

  if (ws_ok) {
    W12 w;
    w.p[0] = (const float*)d_in[5];   // ew1
    w.p[1] = (const float*)d_in[7];   // ew2
    w.p[2] = (const float*)d_in[9];   // nw1
    w.p[3] = (const float*)d_in[11];  // nw2
    w.p[4] = (const float*)d_in[13];  // gw1
    w.p[5] = (const float*)d_in[15];  // gw2
    w.p[6] = (const float*)d_in[17];  // ewih
    w.p[7] = (const float*)d_in[18];  // ewhh
    w.p[8] = (const float*)d_in[21];  // nwih
    w.p[9] = (const float*)d_in[22];  // nwhh
    w.p[10] = (const float*)d_in[25]; // gwih
    w.p[11] = (const float*)d_in[26]; // gwhh
    cvt_kernel<<<(OW_TOTAL / 8 + 255) / 256, 256, 0, stream>>>(w, wbuf);
    hipMemsetAsync(dcnt, 0, (NN + NB) * sizeof(int), stream);
    count_kernel<<<(NE + 255) / 256, 256, 0, stream>>>(ei + NE, batch, dcnt, ncnt);
    scan_kernel<<<1, 256, 0, stream>>>(dcnt, ncnt, rowptr, growptr, fill);
    scatter_kernel<<<(NE + 255) / 256, 256, 0, stream>>>(ei + NE, rowptr, fill, eids);
    // activation bf16 mirrors (x, u only — ea stays f32, see R4 post-mortem)
    cvtbuf_kernel<<<((long)NN * H / 8 + 255) / 256, 256, 0, stream>>>(x, xb, (long)NN * H);
    cvtbuf_kernel<<<((long)NB * H / 8 + 255) / 256, 256, 0, stream>>>(u, ub, (long)NB * H);
  }

  for (int t = 0; t < NSTEPS; ++t) {
    if (ws_ok) {
      edge_kernel<__bf16><<<(NE + 127) / 128, 256, 0, stream>>>(
          xb, ei, ea, ub, batch,
          wbuf + OW_EW1, (const float*)d_in[6], wbuf + OW_EW2, (const float*)d_in[8],
          wbuf + OW_EWIH, wbuf + OW_EWHH, (const float*)d_in[19], (const float*)d_in[20]);
      agg_kernel<<<(NN + 3) / 4, 256, 0, stream>>>(ea, rowptr, eids, aggb);
      node_kernel<__bf16><<<(NN + 127) / 128, 256, 0, stream>>>(
          x, xb, xb, ub, batch, aggb, 1,
          wbuf + OW_NW1, (const float*)d_in[10], wbuf + OW_NW2, (const float*)d_in[12],
          wbuf + OW_NWIH, wbuf + OW_NWHH, (const float*)d_in[23], (const float*)d_in[24]);
      xsum_kernel<<<NB, 256, 0, stream>>>(x, growptr, xsum);
      glob_kernel<__bf16><<<1, 256, 0, stream>>>(
          u, ub, ub, xsum, ncnt,
          wbuf + OW_GW1, (const float*)d_in[14], wbuf + OW_GW2, (const float*)d_in[16],
          wbuf + OW_GWIH, wbuf + OW_GWHH, (const float*)d_in[27], (const float*)d_in[28],
          out, t, 1);
    } else {
      // never-taken safety path: raw f32 weights/activations (row-major), no workspace
      edge_kernel<float><<<(NE + 127) / 128, 256, 0, stream>>>(
          x, ei, ea, u, batch,
          (const float*)d_in[5], (const float*)d_in[6], (const float*)d_in[7], (const float*)d_in[8],
          (const float*)d_in[17], (const float*)d_in[18], (const float*)d_in[19], (const float*)d_in[20]);
      node_kernel<float><<<(NN + 127) / 128, 256, 0, stream>>>(
          x, x, nullptr, u, batch, nullptr, 0,
          (const float*)d_in[9], (const float*)d_in[10], (const float*)d_in[11], (const float*)d_in[12],
          (const float*)d_in[21], (const float*)d_in[22], (const float*)d_in[23], (const float*)d_in[24]);
      glob_kernel<float><<<1, 256, 0, stream>>>(
          u, u, nullptr, xsum, ncnt,
          (const float*)d_in[13], (const float*)d_in[14], (const float*)d_in[15], (const float*)d_in[16],
          (const float*)d_in[25], (const float*)d_in[26], (const float*)d_in[27], (const float*)d_in[28],
          out, t, 0);
    }
  }
}